// Round 8
// baseline (1845.918 us; speedup 1.0000x reference)
//
#include <hip/hip_runtime.h>
#include <stdint.h>

// SelfAttention: B=64,N=8,L=128,E=768,H=12,T=64  (S=512 sets of 128 tokens)
//
// Pipeline (bf16 MFMA, fp32 accum):
//   Xb = bf16(x); Q_h = Xb@Wq[h]^T+bq, P = Xb@(Wv/sqrtE)^T  (batched 256² GEMM)
//   attn per (h,s): scores = Q@Xs^T ; V' = scores@P -> Cat
//   out = Cat @ Wf^T + (bf + Wf@bv)
//
// gemm32: 256x256 tile, BK=32 (24 K-tiles), 8 waves, ring-4 128KiB dynamic
// LDS, mfma_f32_32x32x16_bf16 (16 MFMA/K-tile/wave: half the instruction
// count of 16x16x32 at a better rate), 2 raw barriers + 1 counted vmcnt(8)
// per K-tile, loop-invariant swizzled addressing (offset-immediate folding),
// XCD-chunked zero-tail grid. Ring-2 16x16 fallback if dyn-LDS opt-in fails.

#define EE 768
#define SLOT 50331648L   // shorts per [65536][768] slot

typedef short s16x8 __attribute__((ext_vector_type(8)));
typedef float f32x4 __attribute__((ext_vector_type(4)));
typedef float f32x16 __attribute__((ext_vector_type(16)));

__device__ __forceinline__ short f2bf(float f){
  union { float fv; uint32_t u; } v; v.fv = f;
  uint32_t r = (v.u + 0x7fffu + ((v.u >> 16) & 1u)) >> 16;  // RNE
  return (short)r;
}

__device__ __forceinline__ void gld_lds16(const short* g, short* l){
  __builtin_amdgcn_global_load_lds(
      (const __attribute__((address_space(1))) void*)(uintptr_t)g,
      (__attribute__((address_space(3))) void*)(uintptr_t)l,
      16, 0, 0);
}

// bijective XCD chunking (m204)
__device__ __forceinline__ int xcd_swz(int bid, int nwg){
  int xcd = bid & 7, loc = bid >> 3;
  int q = nwg >> 3, r = nwg & 7;
  return (xcd < r ? xcd * (q + 1) : r * (q + 1) + (xcd - r) * q) + loc;
}

// swizzles (involutions)
__device__ __forceinline__ int swz64(int row, int c){ return c ^ ((row & 7) << 3); }
__device__ __forceinline__ int swz32(int row, int c){ return c ^ (((row >> 1) & 3) << 3); }

// ---------------- casts / small helpers ----------------
__global__ __launch_bounds__(256) void cast_bf16_k(const float* __restrict__ src,
                                                   short* __restrict__ dst,
                                                   long n, float scale){
  long i = ((long)blockIdx.x * 256 + threadIdx.x) * 8;
  if(i >= n) return;
  float4 a = *(const float4*)(src + i);
  float4 b = *(const float4*)(src + i + 4);
  s16x8 o;
  o[0]=f2bf(a.x*scale); o[1]=f2bf(a.y*scale); o[2]=f2bf(a.z*scale); o[3]=f2bf(a.w*scale);
  o[4]=f2bf(b.x*scale); o[5]=f2bf(b.y*scale); o[6]=f2bf(b.z*scale); o[7]=f2bf(b.w*scale);
  *(s16x8*)(dst + i) = o;
}

__global__ __launch_bounds__(256) void cvec_k(const float* __restrict__ Wf,
                                              const float* __restrict__ bv,
                                              const float* __restrict__ bfv,
                                              float* __restrict__ c){
  int e = blockIdx.x * 256 + threadIdx.x;
  if(e >= EE) return;
  float s = bfv[e];
  for(int k = 0; k < EE; ++k) s += Wf[(long)e * EE + k] * bv[k];
  c[e] = s;
}

__global__ __launch_bounds__(256) void bias_build(const float* __restrict__ bq,
                                                  float* __restrict__ biasQP){
  int i = blockIdx.x * 256 + threadIdx.x;
  if(i < 9984) biasQP[i] = (i < 9216) ? bq[i] : 0.f;
}

// ============ ring-4 256² GEMM with 32x32x16 MFMA (dynamic 128 KiB LDS) ============
// Out[g] = A @ W[wh]^T + bias[wh];  K=768 = 24 K-tiles of 32.
template<bool OUTF32>
__global__ __launch_bounds__(512, 1) void gemm32(const short* __restrict__ A,
                                                 const short* __restrict__ W,
                                                 const float* __restrict__ bias,
                                                 void* __restrict__ OutBase,
                                                 int hBase, int nSub, int pSub){
  extern __shared__ short lds[];   // 4 bufs × (A 8192 | B 8192 shorts) = 131072 B
  const int tid = threadIdx.x, lane = tid & 63, w = tid >> 6;
  const int wr = w >> 2, wc = w & 3;           // 2x4 wave grid; wave owns 128x64
  const int bid = xcd_swz(blockIdx.x, nSub * 768);
  const int g = bid / 768, rb = bid - g * 768;
  const int rowBlk = rb / 3, colBlk = rb - rowBlk * 3;
  const long rowA0 = (long)rowBlk * 256;
  const int colB0 = colBlk * 256;
  const int wh = (g == pSub) ? 12 : hBase + g;
  const short* Bm = W + (long)wh * 589824L;

  // staging (proven): wave-instr covers 16 rows x 32 cols; lane: row +lane>>2,
  // col (lane&3)*8, source pre-inverse-swizzled.
  const int slr = w * 16 + (lane >> 2);        // 0..127
  const int scol = swz32(slr, (lane & 3) * 8); // invariant under row+128
  const short* gA0 = A + (rowA0 + slr) * 768 + scol;
  const short* gA1 = A + (rowA0 + 128 + slr) * 768 + scol;
  const short* gB0 = Bm + (long)(colB0 + slr) * 768 + scol;
  const short* gB1 = Bm + (long)(colB0 + 128 + slr) * 768 + scol;

  auto stageK = [&](int kt){
    short* Al = lds + (kt & 3) * 16384;
    gld_lds16(gA0 + kt * 32, Al + (w * 16) * 32);
    gld_lds16(gA1 + kt * 32, Al + (128 + w * 16) * 32);
    gld_lds16(gB0 + kt * 32, Al + 8192 + (w * 16) * 32);
    gld_lds16(gB1 + kt * 32, Al + 8192 + (128 + w * 16) * 32);
  };

  f32x16 acc[4][2] = {};
  const int lrow = lane & 31;          // MFMA row/col within 32-tile
  const int kh = (lane >> 5) * 8;      // k-half offset (shorts)

  auto readAB = [&](int t, int kk, s16x8* Af, s16x8* Bf){
    const short* Al = lds + (t & 3) * 16384;
    const short* Bl = Al + 8192;
    const int colv = kk * 16 + kh;
    #pragma unroll
    for(int rt = 0; rt < 4; ++rt){
      int row = wr * 128 + rt * 32 + lrow;
      Af[rt] = *(const s16x8*)&Al[row * 32 + swz32(row, colv)];
    }
    #pragma unroll
    for(int ct = 0; ct < 2; ++ct){
      int row = wc * 64 + ct * 32 + lrow;
      Bf[ct] = *(const s16x8*)&Bl[row * 32 + swz32(row, colv)];
    }
  };
  auto mm8 = [&](s16x8* Af, s16x8* Bf){
    __builtin_amdgcn_s_setprio(1);
    #pragma unroll
    for(int rt = 0; rt < 4; ++rt)
      #pragma unroll
      for(int ct = 0; ct < 2; ++ct)
        acc[rt][ct] = __builtin_amdgcn_mfma_f32_32x32x16_bf16(Af[rt], Bf[ct], acc[rt][ct], 0, 0, 0);
    __builtin_amdgcn_s_setprio(0);
  };

  // prologue: stage K-tiles 0,1,2 (12 DMA/wave); own tile-0 loads done; barrier
  stageK(0); stageK(1); stageK(2);
  asm volatile("s_waitcnt vmcnt(8)" ::: "memory");
  asm volatile("s_barrier" ::: "memory");

  for(int t = 0; t < 24; ++t){
    s16x8 Af0[4], Bf0[2], Af1[4], Bf1[2];
    readAB(t, 0, Af0, Bf0);
    readAB(t, 1, Af1, Bf1);      // 12 ds_reads up front; latency hides under MFMA
    if(t < 21) stageK(t + 3);    // writes buf (t-1)&3 — reads consumed last iter
    mm8(Af0, Bf0);
    // checkpoint: own K-tile t+1 loads complete (per-wave symmetric counts)
    if(t < 21)       asm volatile("s_waitcnt vmcnt(8)" ::: "memory");
    else if(t == 21) asm volatile("s_waitcnt vmcnt(4)" ::: "memory");
    else if(t == 22) asm volatile("s_waitcnt vmcnt(0)" ::: "memory");
    asm volatile("s_barrier" ::: "memory");
    mm8(Af1, Bf1);
    asm volatile("s_barrier" ::: "memory");
  }

  asm volatile("s_waitcnt vmcnt(0) lgkmcnt(0)" ::: "memory");
  __syncthreads();

  float bb[2];
  #pragma unroll
  for(int ct = 0; ct < 2; ++ct)
    bb[ct] = bias[wh * 768 + colB0 + wc * 64 + ct * 32 + lrow];

  const int rbase = (lane >> 5) * 4;   // C/D: row = (reg&3)+8*(reg>>2)+4*(lane>>5)

  if constexpr(!OUTF32){
    short* Out = (short*)OutBase + (long)g * SLOT;
    short* Cs = lds;  // [128][256]
    #pragma unroll
    for(int ch = 0; ch < 2; ++ch){
      __syncthreads();
      if(wr == ch){
        #pragma unroll
        for(int rt = 0; rt < 4; ++rt)
          #pragma unroll
          for(int ct = 0; ct < 2; ++ct)
            #pragma unroll
            for(int reg = 0; reg < 16; ++reg){
              int row = rt * 32 + rbase + (reg & 3) + 8 * (reg >> 2);
              int c = wc * 64 + ct * 32 + lrow;
              Cs[row * 256 + (c ^ (((row >> 2) & 3) << 4))] = f2bf(acc[rt][ct][reg] + bb[ct]);
            }
      }
      __syncthreads();
      #pragma unroll
      for(int i = 0; i < 8; ++i){
        int idx = i * 512 + tid;
        int row = idx >> 5, cl = (idx & 31) * 8;
        s16x8 v = *(const s16x8*)&Cs[row * 256 + (cl ^ (((row >> 2) & 3) << 4))];
        *(s16x8*)&Out[(rowA0 + ch * 128 + row) * 768 + colB0 + cl] = v;
      }
    }
  } else {
    float* Co = (float*)OutBase;
    #pragma unroll
    for(int rt = 0; rt < 4; ++rt)
      #pragma unroll
      for(int ct = 0; ct < 2; ++ct)
        #pragma unroll
        for(int reg = 0; reg < 16; ++reg){
          long row = rowA0 + wr * 128 + rt * 32 + rbase + (reg & 3) + 8 * (reg >> 2);
          int col = colB0 + wc * 64 + ct * 32 + lrow;
          Co[row * 768 + col] = acc[rt][ct][reg] + bb[ct];
        }
  }
}

// ============ FALLBACK: proven ring-2 16x16 kernels ============
__global__ __launch_bounds__(512, 1) void gemm256(const short* __restrict__ A,
                                                  const short* __restrict__ W,
                                                  const float* __restrict__ bias,
                                                  short* __restrict__ OutBase,
                                                  int hBase, int nSub, int pSub){
  __shared__ short lds[2][16384];
  const int tid = threadIdx.x, lane = tid & 63, w = tid >> 6;
  const int wr = w >> 2, wc = w & 3;
  const int bid = xcd_swz(blockIdx.x, nSub * 768);
  const int g = bid / 768, rb = bid - g * 768;
  const int rowBlk = rb / 3, colBlk = rb - rowBlk * 3;
  const long rowA0 = (long)rowBlk * 256;
  const int colB0 = colBlk * 256;
  const int wh = (g == pSub) ? 12 : hBase + g;
  const short* Bm = W + (long)wh * 589824L;
  short* Out = OutBase + (long)g * SLOT;

  const int sr0 = w * 32 + (lane >> 2);
  const int sr1 = sr0 + 16;
  const int scol = (lane & 3) * 8;
  const int sc0 = swz32(sr0, scol);
  const int sc1 = swz32(sr1, scol);
  const short* Ar0 = A + (rowA0 + sr0) * 768;
  const short* Ar1 = A + (rowA0 + sr1) * 768;
  const short* Br0 = Bm + (long)(colB0 + sr0) * 768;
  const short* Br1 = Bm + (long)(colB0 + sr1) * 768;

  f32x4 acc[8][4] = {};
  s16x8 af[4], bf0[2], bf1[2];
  const int fr = lane & 15, fc = (lane >> 4) * 8;

  auto stage = [&](int b, int kt){
    short* Al = &lds[b][0];
    short* Bl = &lds[b][8192];
    gld_lds16(Ar0 + kt + sc0, Al + (w * 2) * 512);
    gld_lds16(Ar1 + kt + sc1, Al + (w * 2 + 1) * 512);
    gld_lds16(Br0 + kt + sc0, Bl + (w * 2) * 512);
    gld_lds16(Br1 + kt + sc1, Bl + (w * 2 + 1) * 512);
  };

  stage(0, 0);
  for(int t = 0; t < 24; ++t){
    if(t < 23){
      stage((t + 1) & 1, (t + 1) * 32);
      asm volatile("s_waitcnt vmcnt(4)\n\ts_barrier" ::: "memory");
    } else {
      asm volatile("s_waitcnt vmcnt(0)\n\ts_barrier" ::: "memory");
    }
    const short* Al = &lds[t & 1][0];
    const short* Bl = &lds[t & 1][8192];

    auto loadA = [&](int mh){
      #pragma unroll
      for(int m = 0; m < 4; ++m){
        int row = wr * 128 + (mh * 4 + m) * 16 + fr;
        af[m] = *(const s16x8*)&Al[row * 32 + swz32(row, fc)];
      }
    };
    auto loadB = [&](int nh, s16x8* bf){
      #pragma unroll
      for(int n = 0; n < 2; ++n){
        int row = wc * 64 + (nh * 2 + n) * 16 + fr;
        bf[n] = *(const s16x8*)&Bl[row * 32 + swz32(row, fc)];
      }
    };
    auto mm = [&](int mh, int nh, s16x8* bf){
      __builtin_amdgcn_s_setprio(1);
      #pragma unroll
      for(int m = 0; m < 4; ++m)
        #pragma unroll
        for(int n = 0; n < 2; ++n)
          acc[mh * 4 + m][nh * 2 + n] = __builtin_amdgcn_mfma_f32_16x16x32_bf16(
              af[m], bf[n], acc[mh * 4 + m][nh * 2 + n], 0, 0, 0);
      __builtin_amdgcn_s_setprio(0);
    };

    loadA(0); loadB(0, bf0); mm(0, 0, bf0);
    loadB(1, bf1);           mm(0, 1, bf1);
    loadA(1);                mm(1, 1, bf1);
    loadB(0, bf0);           mm(1, 0, bf0);
    asm volatile("s_barrier" ::: "memory");
  }

  float bb[4];
  #pragma unroll
  for(int n = 0; n < 4; ++n)
    bb[n] = bias[wh * 768 + colB0 + wc * 64 + n * 16 + fr];

  short* Cs = &lds[0][0];
  #pragma unroll
  for(int ch = 0; ch < 2; ++ch){
    __syncthreads();
    if(wr == ch){
      #pragma unroll
      for(int m = 0; m < 8; ++m)
        #pragma unroll
        for(int n = 0; n < 4; ++n)
          #pragma unroll
          for(int r2 = 0; r2 < 4; ++r2){
            int row = m * 16 + (lane >> 4) * 4 + r2;
            int c = wc * 64 + n * 16 + fr;
            Cs[row * 256 + (c ^ (((row >> 2) & 3) << 4))] = f2bf(acc[m][n][r2] + bb[n]);
          }
    }
    __syncthreads();
    #pragma unroll
    for(int i = 0; i < 8; ++i){
      int idx = i * 512 + tid;
      int row = idx >> 5, cl = (idx & 31) * 8;
      s16x8 v = *(const s16x8*)&Cs[row * 256 + (cl ^ (((row >> 2) & 3) << 4))];
      *(s16x8*)&Out[(rowA0 + ch * 128 + row) * 768 + colB0 + cl] = v;
    }
  }
}

__global__ __launch_bounds__(256, 2) void gemm_f32(const short* __restrict__ A,
                                                   const short* __restrict__ B,
                                                   const float* __restrict__ bias,
                                                   float* __restrict__ Cout){
  __shared__ short smem[4 * 8192];
  const int tid = threadIdx.x, lane = tid & 63, w = tid >> 6;
  const int wr = w >> 1, wc = w & 1;
  const int nCol = 6;
  const int xcd = blockIdx.x & 7, loc = blockIdx.x >> 3;
  const int width = nCol << 3;
  const int gid = loc / width, rem = loc % width;
  const int rowBlk = (xcd << 6) + (gid << 3) + (rem & 7);
  const int colBlk = rem >> 3;
  const long rowA0 = (long)rowBlk << 7;
  const long colB0 = (long)colBlk << 7;
  const int lr = lane >> 3;
  const int sA = swz64(lr, (lane & 7) * 8);

  f32x4 acc[4][4] = {};
  auto stage = [&](int b, int kt){
    short* As = smem + b * 16384;
    #pragma unroll
    for(int it = 0; it < 4; ++it){
      int r = it * 32 + w * 8;
      gld_lds16(&A[(rowA0 + r + lr) * 768 + kt + sA], &As[r * 64]);
      gld_lds16(&B[(colB0 + r + lr) * 768 + kt + sA], &As[8192 + r * 64]);
    }
  };

  stage(0, 0);
  for(int t = 0; t < 12; ++t){
    const int cur = t & 1;
    if(t < 11){
      stage(cur ^ 1, (t + 1) * 64);
      asm volatile("s_waitcnt vmcnt(8)\n\ts_barrier" ::: "memory");
    } else {
      asm volatile("s_waitcnt vmcnt(0)\n\ts_barrier" ::: "memory");
    }
    const short* As = smem + cur * 16384;
    const short* Bs = As + 8192;
    #pragma unroll
    for(int kk = 0; kk < 2; ++kk){
      s16x8 af[4], bfr[4];
      #pragma unroll
      for(int m = 0; m < 4; ++m){
        int row = wr * 64 + m * 16 + (lane & 15);
        af[m] = *(const s16x8*)&As[row * 64 + swz64(row, kk * 32 + (lane >> 4) * 8)];
      }
      #pragma unroll
      for(int n = 0; n < 4; ++n){
        int row = wc * 64 + n * 16 + (lane & 15);
        bfr[n] = *(const s16x8*)&Bs[row * 64 + swz64(row, kk * 32 + (lane >> 4) * 8)];
      }
      #pragma unroll
      for(int m = 0; m < 4; ++m)
        #pragma unroll
        for(int n = 0; n < 4; ++n)
          acc[m][n] = __builtin_amdgcn_mfma_f32_16x16x32_bf16(af[m], bfr[n], acc[m][n], 0, 0, 0);
    }
    asm volatile("s_barrier" ::: "memory");
  }

  const long crow0 = rowA0 + wr * 64;
  const long ccol0 = colB0 + wc * 64;
  #pragma unroll
  for(int n = 0; n < 4; ++n){
    const long col = ccol0 + n * 16 + (lane & 15);
    const float bbv = bias[col];
    #pragma unroll
    for(int m = 0; m < 4; ++m)
      #pragma unroll
      for(int r = 0; r < 4; ++r){
        const long row = crow0 + m * 16 + (lane >> 4) * 4 + r;
        Cout[row * 768 + col] = acc[m][n][r] + bbv;
      }
  }
}

// ------ fused per-(h,s): scores = Q@Xs^T ; V' = scores@P ; -> Cat -----------
__global__ __launch_bounds__(256, 2) void attn_k(const short* __restrict__ Q,
                                                 const short* __restrict__ P,
                                                 const short* __restrict__ X,
                                                 short* __restrict__ Cat,
                                                 int h0, int nH){
  __shared__ short smem[4 * 8192];
  const int tid = threadIdx.x, lane = tid & 63, w = tid >> 6;
  const int wr = w >> 1, wc = w & 1;
  const int nwg = nH << 9;
  const int bid = xcd_swz(blockIdx.x, nwg);
  const int s = bid / nH, hi = bid - s * nH, h = h0 + hi;
  const long row0 = (long)s * 128;
  const int lr = lane >> 3;
  const int sA = swz64(lr, (lane & 7) * 8);

  const int pm = tid >> 3, pt0 = (tid & 7) * 8;
  s16x8 pv[4];
  #pragma unroll
  for(int i = 0; i < 4; ++i)
    pv[i] = *(const s16x8*)&P[(row0 + pm + i * 32) * 768L + h * 64 + pt0];

  f32x4 acc[4][4] = {};
  const short* Qh = Q + (long)hi * SLOT;
  auto stage = [&](int b, int kt){
    short* As = smem + b * 16384;
    #pragma unroll
    for(int it = 0; it < 4; ++it){
      int r = it * 32 + w * 8;
      gld_lds16(&Qh[(row0 + r + lr) * 768L + kt + sA], &As[r * 64]);
      gld_lds16(&X[(row0 + r + lr) * 768L + kt + sA], &As[8192 + r * 64]);
    }
  };

  stage(0, 0);
  for(int t = 0; t < 12; ++t){
    const int cur = t & 1;
    if(t < 11){
      stage(cur ^ 1, (t + 1) * 64);
      asm volatile("s_waitcnt vmcnt(8)\n\ts_barrier" ::: "memory");
    } else {
      asm volatile("s_waitcnt vmcnt(0)\n\ts_barrier" ::: "memory");
    }
    const short* As = smem + cur * 16384;
    const short* Bs = As + 8192;
    #pragma unroll
    for(int kk = 0; kk < 2; ++kk){
      s16x8 af[4], bfr[4];
      #pragma unroll
      for(int m = 0; m < 4; ++m){
        int row = wr * 64 + m * 16 + (lane & 15);
        af[m] = *(const s16x8*)&As[row * 64 + swz64(row, kk * 32 + (lane >> 4) * 8)];
      }
      #pragma unroll
      for(int n = 0; n < 4; ++n){
        int row = wc * 64 + n * 16 + (lane & 15);
        bfr[n] = *(const s16x8*)&Bs[row * 64 + swz64(row, kk * 32 + (lane >> 4) * 8)];
      }
      #pragma unroll
      for(int m = 0; m < 4; ++m)
        #pragma unroll
        for(int n = 0; n < 4; ++n)
          acc[m][n] = __builtin_amdgcn_mfma_f32_16x16x32_bf16(af[m], bfr[n], acc[m][n], 0, 0, 0);
    }
    asm volatile("s_barrier" ::: "memory");
  }

  short* Pt = smem;           // [64][128]
  short* Vt = smem + 8192;    // [128][64]
  short* Ss = smem + 16384;   // [128][128]

  #pragma unroll
  for(int m = 0; m < 4; ++m)
    #pragma unroll
    for(int n = 0; n < 4; ++n)
      #pragma unroll
      for(int r = 0; r < 4; ++r){
        int row = wr * 64 + m * 16 + (lane >> 4) * 4 + r;
        int c = wc * 64 + n * 16 + (lane & 15);
        Ss[row * 128 + swz64(row, c)] = f2bf(acc[m][n][r]);
      }
  #pragma unroll
  for(int i = 0; i < 4; ++i)
    #pragma unroll
    for(int j = 0; j < 8; ++j){
      int trow = pt0 + j;
      int mc = pm + i * 32;
      Pt[trow * 128 + swz64(trow, mc)] = pv[i][j];
    }
  __syncthreads();

  f32x4 accv[2][4] = {};
  #pragma unroll
  for(int kk = 0; kk < 4; ++kk){
    s16x8 a2[2], b4[4];
    #pragma unroll
    for(int m = 0; m < 2; ++m){
      int row = w * 32 + m * 16 + (lane & 15);
      a2[m] = *(const s16x8*)&Ss[row * 128 + swz64(row, kk * 32 + (lane >> 4) * 8)];
    }
    #pragma unroll
    for(int n = 0; n < 4; ++n){
      int trow = n * 16 + (lane & 15);
      b4[n] = *(const s16x8*)&Pt[trow * 128 + swz64(trow, kk * 32 + (lane >> 4) * 8)];
    }
    #pragma unroll
    for(int m = 0; m < 2; ++m)
      #pragma unroll
      for(int n = 0; n < 4; ++n)
        accv[m][n] = __builtin_amdgcn_mfma_f32_16x16x32_bf16(a2[m], b4[n], accv[m][n], 0, 0, 0);
  }

  #pragma unroll
  for(int m = 0; m < 2; ++m)
    #pragma unroll
    for(int n = 0; n < 4; ++n)
      #pragma unroll
      for(int r = 0; r < 4; ++r){
        int row = w * 32 + m * 16 + (lane >> 4) * 4 + r;
        int c = n * 16 + (lane & 15);
        Vt[row * 64 + swz64(row, c)] = f2bf(accv[m][n][r]);
      }
  __syncthreads();
  #pragma unroll
  for(int k2 = 0; k2 < 4; ++k2){
    int row = k2 * 32 + (tid >> 3);
    int cl = (tid & 7) * 8;
    s16x8 v = *(const s16x8*)&Vt[row * 64 + swz64(row, cl)];
    *(s16x8*)&Cat[(row0 + row) * 768L + h * 64 + cl] = v;
  }
}

extern "C" void kernel_launch(void* const* d_in, const int* in_sizes, int n_in,
                              void* d_out, int out_size, void* d_ws, size_t ws_size,
                              hipStream_t stream){
  const float* x  = (const float*)d_in[0];
  const float* Wq = (const float*)d_in[1];
  const float* bq = (const float*)d_in[2];
  const float* Wv = (const float*)d_in[3];
  const float* bv = (const float*)d_in[4];
  const float* Wf = (const float*)d_in[5];
  const float* bfv= (const float*)d_in[6];

  const float rsqE = 0.03608439182435161f;  // 1/sqrt(768)
  char* ws = (char*)d_ws;

  short* Xb  = (short*)(ws);
  short* Cat = (short*)(ws + 100663296L);
  short* Wb  = (short*)(ws + 201326592L);   // [13*768][768] bf16
  short* Wfb = (short*)(ws + 216662016L);
  float* bQP = (float*)(ws + 217841664L);   // [9984]
  float* cv  = (float*)(ws + 217881600L);
  short* QS  = (short*)(ws + 217884672L);   // (G+1) slots of [65536][768]

  const size_t QOFF = 217884672ULL;
  int G = 1;
  const int cands[5] = {12, 6, 4, 3, 2};
  for(int i = 0; i < 5; ++i)
    if(ws_size >= QOFF + (size_t)(cands[i] + 1) * 100663296ULL){ G = cands[i]; break; }
  short* Pall = QS + (long)G * SLOT;

  // opt-in to 128 KiB dynamic LDS; fall back to ring-2 kernels if unavailable
  bool deep =
      hipFuncSetAttribute(reinterpret_cast<const void*>(&gemm32<false>),
                          hipFuncAttributeMaxDynamicSharedMemorySize, 131072) == hipSuccess &&
      hipFuncSetAttribute(reinterpret_cast<const void*>(&gemm32<true>),
                          hipFuncAttributeMaxDynamicSharedMemorySize, 131072) == hipSuccess;

  dim3 b256(256), b512(512);
  cast_bf16_k<<<24576, b256, 0, stream>>>(x,  Xb, 50331648L, 1.f);
  cast_bf16_k<<<3456,  b256, 0, stream>>>(Wq, Wb, 7077888L, 1.f);
  cast_bf16_k<<<288,   b256, 0, stream>>>(Wv, Wb + 7077888L, 589824L, rsqE);
  cast_bf16_k<<<288,   b256, 0, stream>>>(Wf, Wfb, 589824L, 1.f);
  bias_build<<<39, b256, 0, stream>>>(bq, bQP);
  cvec_k<<<3, b256, 0, stream>>>(Wf, bv, bfv, cv);

  const int nB = 12 / G;
  for(int b = 0; b < nB; ++b){
    const int nSub = G + (b == 0 ? 1 : 0);
    const int pSub = (b == 0) ? G : -1;
    if(deep)
      gemm32<false><<<dim3(nSub * 768), b512, 131072, stream>>>(Xb, Wb, bQP, QS, b * G, nSub, pSub);
    else
      gemm256<<<dim3(nSub * 768), b512, 0, stream>>>(Xb, Wb, bQP, QS, b * G, nSub, pSub);
    attn_k<<<dim3(G * 512), b256, 0, stream>>>(QS, Pall, Xb, Cat, b * G, G);
  }
  if(deep)
    gemm32<true><<<dim3(768), b512, 131072, stream>>>(Cat, Wfb, cv, d_out, 0, 1, -1);
  else
    gemm_f32<<<dim3(3072), b256, 0, stream>>>(Cat, Wfb, cv, (float*)d_out);
}

// Round 9
// 1742.678 us; speedup vs baseline: 1.0592x; 1.0592x over previous
//
#include <hip/hip_runtime.h>
#include <stdint.h>

// SelfAttention: B=64,N=8,L=128,E=768,H=12,T=64  (S=512 sets of 128 tokens)
//
// Pipeline (bf16 MFMA, fp32 accum):
//   Xb = bf16(x); Q_h = Xb@Wq[h]^T+bq, P = Xb@(Wv/sqrtE)^T  (batched 256² GEMM)
//   attn per (h,s): scores = Q@Xs^T ; V' = scores@P -> Cat
//   out = Cat @ Wf^T + (bf + Wf@bv)
//
// gemm64: 256x256 tile, BK=64 (12 K-steps), 8 waves, ring-2 128KiB dynamic
// LDS, 2 barriers + 1 counted vmcnt(8) per K-step (64 MFMA/wave per barrier
// pair — 2x the amortization of the BK=32 variants that all plateaued at
// ~37-40% MfmaUtil), 16-row fragment reads with swz64 (measured 0-conflict),
// XCD-chunked zero-tail grid. Ring-2 BK=32 fallback if dyn-LDS opt-in fails.

#define EE 768
#define SLOT 50331648L   // shorts per [65536][768] slot

typedef short s16x8 __attribute__((ext_vector_type(8)));
typedef float f32x4 __attribute__((ext_vector_type(4)));

__device__ __forceinline__ short f2bf(float f){
  union { float fv; uint32_t u; } v; v.fv = f;
  uint32_t r = (v.u + 0x7fffu + ((v.u >> 16) & 1u)) >> 16;  // RNE
  return (short)r;
}

__device__ __forceinline__ void gld_lds16(const short* g, short* l){
  __builtin_amdgcn_global_load_lds(
      (const __attribute__((address_space(1))) void*)(uintptr_t)g,
      (__attribute__((address_space(3))) void*)(uintptr_t)l,
      16, 0, 0);
}

// bijective XCD chunking (m204)
__device__ __forceinline__ int xcd_swz(int bid, int nwg){
  int xcd = bid & 7, loc = bid >> 3;
  int q = nwg >> 3, r = nwg & 7;
  return (xcd < r ? xcd * (q + 1) : r * (q + 1) + (xcd - r) * q) + loc;
}

// swizzles (involutions)
__device__ __forceinline__ int swz64(int row, int c){ return c ^ ((row & 7) << 3); }
__device__ __forceinline__ int swz32(int row, int c){ return c ^ (((row >> 1) & 3) << 3); }

// ---------------- casts / small helpers ----------------
__global__ __launch_bounds__(256) void cast_bf16_k(const float* __restrict__ src,
                                                   short* __restrict__ dst,
                                                   long n, float scale){
  long i = ((long)blockIdx.x * 256 + threadIdx.x) * 8;
  if(i >= n) return;
  float4 a = *(const float4*)(src + i);
  float4 b = *(const float4*)(src + i + 4);
  s16x8 o;
  o[0]=f2bf(a.x*scale); o[1]=f2bf(a.y*scale); o[2]=f2bf(a.z*scale); o[3]=f2bf(a.w*scale);
  o[4]=f2bf(b.x*scale); o[5]=f2bf(b.y*scale); o[6]=f2bf(b.z*scale); o[7]=f2bf(b.w*scale);
  *(s16x8*)(dst + i) = o;
}

__global__ __launch_bounds__(256) void cvec_k(const float* __restrict__ Wf,
                                              const float* __restrict__ bv,
                                              const float* __restrict__ bfv,
                                              float* __restrict__ c){
  int e = blockIdx.x * 256 + threadIdx.x;
  if(e >= EE) return;
  float s = bfv[e];
  for(int k = 0; k < EE; ++k) s += Wf[(long)e * EE + k] * bv[k];
  c[e] = s;
}

__global__ __launch_bounds__(256) void bias_build(const float* __restrict__ bq,
                                                  float* __restrict__ biasQP){
  int i = blockIdx.x * 256 + threadIdx.x;
  if(i < 9984) biasQP[i] = (i < 9216) ? bq[i] : 0.f;
}

// ============ BK=64 ring-2 256² GEMM (dynamic 128 KiB LDS) ============
// Out[g] = A @ W[wh]^T + bias[wh];  K=768 = 12 K-steps of 64.
__global__ __launch_bounds__(512, 1) void gemm64(const short* __restrict__ A,
                                                 const short* __restrict__ W,
                                                 const float* __restrict__ bias,
                                                 short* __restrict__ OutBase,
                                                 int hBase, int nSub, int pSub){
  extern __shared__ short lds[];   // 2 bufs × (A 16384 | B 16384 shorts) = 131072 B
  const int tid = threadIdx.x, lane = tid & 63, w = tid >> 6;
  const int wr = w >> 2, wc = w & 3;           // 2x4 wave grid; wave owns 128x64
  const int bid = xcd_swz(blockIdx.x, nSub * 768);
  const int g = bid / 768, rb = bid - g * 768;
  const int rowBlk = rb / 3, colBlk = rb - rowBlk * 3;
  const long rowA0 = (long)rowBlk * 256;
  const int colB0 = colBlk * 256;
  const int wh = (g == pSub) ? 12 : hBase + g;
  const short* Bm = W + (long)wh * 589824L;

  // staging: code-line j = one wave-instr per wave; global index
  // = j*8192B + w*1024B + lane*16B  ->  row = j*64 + tid>>3, colseg (tid&7)*8.
  // Source col pre-inverse-swizzled (row&7 = (tid>>3)&7, invariant in j).
  const int srow = tid >> 3;                    // 0..63
  const int ssw = swz64(srow, (tid & 7) * 8);   // pre-swizzled source col
  const short* gA = A + (rowA0 + srow) * 768 + ssw;
  const short* gB = Bm + (long)(colB0 + srow) * 768 + ssw;

  auto stage = [&](int b, int kt){
    short* Al = lds + b * 32768;
    short* Bl = Al + 16384;
    #pragma unroll
    for(int j = 0; j < 4; ++j){
      gld_lds16(gA + (long)j * 49152 + kt, Al + j * 4096 + w * 512);
      gld_lds16(gB + (long)j * 49152 + kt, Bl + j * 4096 + w * 512);
    }
  };

  f32x4 acc[8][4] = {};
  const int fr = lane & 15, fcb = (lane >> 4) * 8;

  stage(0, 0);
  for(int t = 0; t < 12; ++t){
    if(t < 11){
      stage((t + 1) & 1, (t + 1) * 64);
      asm volatile("s_waitcnt vmcnt(8)\n\ts_barrier" ::: "memory");
    } else {
      asm volatile("s_waitcnt vmcnt(0)\n\ts_barrier" ::: "memory");
    }
    const short* Al = lds + (t & 1) * 32768;
    const short* Bl = Al + 16384;

    #pragma unroll
    for(int kk = 0; kk < 2; ++kk){
      s16x8 af[8], bf[4];
      const int colv = kk * 32 + fcb;
      #pragma unroll
      for(int m = 0; m < 8; ++m){
        int row = wr * 128 + m * 16 + fr;
        af[m] = *(const s16x8*)&Al[row * 64 + swz64(row, colv)];
      }
      #pragma unroll
      for(int n = 0; n < 4; ++n){
        int row = wc * 64 + n * 16 + fr;
        bf[n] = *(const s16x8*)&Bl[row * 64 + swz64(row, colv)];
      }
      __builtin_amdgcn_s_setprio(1);
      #pragma unroll
      for(int m = 0; m < 8; ++m)
        #pragma unroll
        for(int n = 0; n < 4; ++n)
          acc[m][n] = __builtin_amdgcn_mfma_f32_16x16x32_bf16(af[m], bf[n], acc[m][n], 0, 0, 0);
      __builtin_amdgcn_s_setprio(0);
    }
    asm volatile("s_barrier" ::: "memory");
  }

  asm volatile("s_waitcnt vmcnt(0) lgkmcnt(0)" ::: "memory");
  __syncthreads();

  float bb[4];
  #pragma unroll
  for(int n = 0; n < 4; ++n)
    bb[n] = bias[wh * 768 + colB0 + wc * 64 + n * 16 + fr];

  short* Out = OutBase + (long)g * SLOT;
  short* Cs = lds;  // [128][256] overlay on dead staging
  #pragma unroll
  for(int ch = 0; ch < 2; ++ch){
    __syncthreads();
    if(wr == ch){
      #pragma unroll
      for(int m = 0; m < 8; ++m)
        #pragma unroll
        for(int n = 0; n < 4; ++n)
          #pragma unroll
          for(int r2 = 0; r2 < 4; ++r2){
            int row = m * 16 + (lane >> 4) * 4 + r2;
            int c = wc * 64 + n * 16 + fr;
            Cs[row * 256 + (c ^ (((row >> 2) & 3) << 4))] = f2bf(acc[m][n][r2] + bb[n]);
          }
    }
    __syncthreads();
    #pragma unroll
    for(int i = 0; i < 8; ++i){
      int idx = i * 512 + tid;
      int row = idx >> 5, cl = (idx & 31) * 8;
      s16x8 v = *(const s16x8*)&Cs[row * 256 + (cl ^ (((row >> 2) & 3) << 4))];
      *(s16x8*)&Out[(rowA0 + ch * 128 + row) * 768 + colB0 + cl] = v;
    }
  }
}

// ============ FALLBACK: proven round-4 ring-2 BK=32 kernel ============
__global__ __launch_bounds__(512, 1) void gemm256(const short* __restrict__ A,
                                                  const short* __restrict__ W,
                                                  const float* __restrict__ bias,
                                                  short* __restrict__ OutBase,
                                                  int hBase, int nSub, int pSub){
  __shared__ short lds[2][16384];
  const int tid = threadIdx.x, lane = tid & 63, w = tid >> 6;
  const int wr = w >> 2, wc = w & 3;
  const int bid = xcd_swz(blockIdx.x, nSub * 768);
  const int g = bid / 768, rb = bid - g * 768;
  const int rowBlk = rb / 3, colBlk = rb - rowBlk * 3;
  const long rowA0 = (long)rowBlk * 256;
  const int colB0 = colBlk * 256;
  const int wh = (g == pSub) ? 12 : hBase + g;
  const short* Bm = W + (long)wh * 589824L;
  short* Out = OutBase + (long)g * SLOT;

  const int sr0 = w * 32 + (lane >> 2);
  const int sr1 = sr0 + 16;
  const int scol = (lane & 3) * 8;
  const int sc0 = swz32(sr0, scol);
  const int sc1 = swz32(sr1, scol);
  const short* Ar0 = A + (rowA0 + sr0) * 768;
  const short* Ar1 = A + (rowA0 + sr1) * 768;
  const short* Br0 = Bm + (long)(colB0 + sr0) * 768;
  const short* Br1 = Bm + (long)(colB0 + sr1) * 768;

  f32x4 acc[8][4] = {};
  s16x8 af[4], bf0[2], bf1[2];
  const int fr = lane & 15, fc = (lane >> 4) * 8;

  auto stage = [&](int b, int kt){
    short* Al = &lds[b][0];
    short* Bl = &lds[b][8192];
    gld_lds16(Ar0 + kt + sc0, Al + (w * 2) * 512);
    gld_lds16(Ar1 + kt + sc1, Al + (w * 2 + 1) * 512);
    gld_lds16(Br0 + kt + sc0, Bl + (w * 2) * 512);
    gld_lds16(Br1 + kt + sc1, Bl + (w * 2 + 1) * 512);
  };

  stage(0, 0);
  for(int t = 0; t < 24; ++t){
    if(t < 23){
      stage((t + 1) & 1, (t + 1) * 32);
      asm volatile("s_waitcnt vmcnt(4)\n\ts_barrier" ::: "memory");
    } else {
      asm volatile("s_waitcnt vmcnt(0)\n\ts_barrier" ::: "memory");
    }
    const short* Al = &lds[t & 1][0];
    const short* Bl = &lds[t & 1][8192];

    auto loadA = [&](int mh){
      #pragma unroll
      for(int m = 0; m < 4; ++m){
        int row = wr * 128 + (mh * 4 + m) * 16 + fr;
        af[m] = *(const s16x8*)&Al[row * 32 + swz32(row, fc)];
      }
    };
    auto loadB = [&](int nh, s16x8* bf){
      #pragma unroll
      for(int n = 0; n < 2; ++n){
        int row = wc * 64 + (nh * 2 + n) * 16 + fr;
        bf[n] = *(const s16x8*)&Bl[row * 32 + swz32(row, fc)];
      }
    };
    auto mm = [&](int mh, int nh, s16x8* bf){
      __builtin_amdgcn_s_setprio(1);
      #pragma unroll
      for(int m = 0; m < 4; ++m)
        #pragma unroll
        for(int n = 0; n < 2; ++n)
          acc[mh * 4 + m][nh * 2 + n] = __builtin_amdgcn_mfma_f32_16x16x32_bf16(
              af[m], bf[n], acc[mh * 4 + m][nh * 2 + n], 0, 0, 0);
      __builtin_amdgcn_s_setprio(0);
    };

    loadA(0); loadB(0, bf0); mm(0, 0, bf0);
    loadB(1, bf1);           mm(0, 1, bf1);
    loadA(1);                mm(1, 1, bf1);
    loadB(0, bf0);           mm(1, 0, bf0);
    asm volatile("s_barrier" ::: "memory");
  }

  float bb[4];
  #pragma unroll
  for(int n = 0; n < 4; ++n)
    bb[n] = bias[wh * 768 + colB0 + wc * 64 + n * 16 + fr];

  short* Cs = &lds[0][0];
  #pragma unroll
  for(int ch = 0; ch < 2; ++ch){
    __syncthreads();
    if(wr == ch){
      #pragma unroll
      for(int m = 0; m < 8; ++m)
        #pragma unroll
        for(int n = 0; n < 4; ++n)
          #pragma unroll
          for(int r2 = 0; r2 < 4; ++r2){
            int row = m * 16 + (lane >> 4) * 4 + r2;
            int c = wc * 64 + n * 16 + fr;
            Cs[row * 256 + (c ^ (((row >> 2) & 3) << 4))] = f2bf(acc[m][n][r2] + bb[n]);
          }
    }
    __syncthreads();
    #pragma unroll
    for(int i = 0; i < 8; ++i){
      int idx = i * 512 + tid;
      int row = idx >> 5, cl = (idx & 31) * 8;
      s16x8 v = *(const s16x8*)&Cs[row * 256 + (cl ^ (((row >> 2) & 3) << 4))];
      *(s16x8*)&Out[(rowA0 + ch * 128 + row) * 768 + colB0 + cl] = v;
    }
  }
}

// ------ final C[M,768] = A @ B^T + bias (fp32 out); 128² 2-phase (proven) ------
__global__ __launch_bounds__(256, 2) void gemm_f32(const short* __restrict__ A,
                                                   const short* __restrict__ B,
                                                   const float* __restrict__ bias,
                                                   float* __restrict__ Cout){
  __shared__ short smem[4 * 8192];
  const int tid = threadIdx.x, lane = tid & 63, w = tid >> 6;
  const int wr = w >> 1, wc = w & 1;
  const int nCol = 6;
  const int xcd = blockIdx.x & 7, loc = blockIdx.x >> 3;
  const int width = nCol << 3;
  const int gid = loc / width, rem = loc % width;
  const int rowBlk = (xcd << 6) + (gid << 3) + (rem & 7);
  const int colBlk = rem >> 3;
  const long rowA0 = (long)rowBlk << 7;
  const long colB0 = (long)colBlk << 7;
  const int lr = lane >> 3;
  const int sA = swz64(lr, (lane & 7) * 8);

  f32x4 acc[4][4] = {};
  auto stage = [&](int b, int kt){
    short* As = smem + b * 16384;
    #pragma unroll
    for(int it = 0; it < 4; ++it){
      int r = it * 32 + w * 8;
      gld_lds16(&A[(rowA0 + r + lr) * 768 + kt + sA], &As[r * 64]);
      gld_lds16(&B[(colB0 + r + lr) * 768 + kt + sA], &As[8192 + r * 64]);
    }
  };

  stage(0, 0);
  for(int t = 0; t < 12; ++t){
    const int cur = t & 1;
    if(t < 11){
      stage(cur ^ 1, (t + 1) * 64);
      asm volatile("s_waitcnt vmcnt(8)\n\ts_barrier" ::: "memory");
    } else {
      asm volatile("s_waitcnt vmcnt(0)\n\ts_barrier" ::: "memory");
    }
    const short* As = smem + cur * 16384;
    const short* Bs = As + 8192;
    #pragma unroll
    for(int kk = 0; kk < 2; ++kk){
      s16x8 af[4], bfr[4];
      #pragma unroll
      for(int m = 0; m < 4; ++m){
        int row = wr * 64 + m * 16 + (lane & 15);
        af[m] = *(const s16x8*)&As[row * 64 + swz64(row, kk * 32 + (lane >> 4) * 8)];
      }
      #pragma unroll
      for(int n = 0; n < 4; ++n){
        int row = wc * 64 + n * 16 + (lane & 15);
        bfr[n] = *(const s16x8*)&Bs[row * 64 + swz64(row, kk * 32 + (lane >> 4) * 8)];
      }
      #pragma unroll
      for(int m = 0; m < 4; ++m)
        #pragma unroll
        for(int n = 0; n < 4; ++n)
          acc[m][n] = __builtin_amdgcn_mfma_f32_16x16x32_bf16(af[m], bfr[n], acc[m][n], 0, 0, 0);
    }
    asm volatile("s_barrier" ::: "memory");
  }

  const long crow0 = rowA0 + wr * 64;
  const long ccol0 = colB0 + wc * 64;
  #pragma unroll
  for(int n = 0; n < 4; ++n){
    const long col = ccol0 + n * 16 + (lane & 15);
    const float bbv = bias[col];
    #pragma unroll
    for(int m = 0; m < 4; ++m)
      #pragma unroll
      for(int r = 0; r < 4; ++r){
        const long row = crow0 + m * 16 + (lane >> 4) * 4 + r;
        Cout[row * 768 + col] = acc[m][n][r] + bbv;
      }
  }
}

// ------ fused per-(h,s): scores = Q@Xs^T ; V' = scores@P ; -> Cat -----------
__global__ __launch_bounds__(256, 2) void attn_k(const short* __restrict__ Q,
                                                 const short* __restrict__ P,
                                                 const short* __restrict__ X,
                                                 short* __restrict__ Cat,
                                                 int h0, int nH){
  __shared__ short smem[4 * 8192];
  const int tid = threadIdx.x, lane = tid & 63, w = tid >> 6;
  const int wr = w >> 1, wc = w & 1;
  const int nwg = nH << 9;
  const int bid = xcd_swz(blockIdx.x, nwg);
  const int s = bid / nH, hi = bid - s * nH, h = h0 + hi;
  const long row0 = (long)s * 128;
  const int lr = lane >> 3;
  const int sA = swz64(lr, (lane & 7) * 8);

  const int pm = tid >> 3, pt0 = (tid & 7) * 8;
  s16x8 pv[4];
  #pragma unroll
  for(int i = 0; i < 4; ++i)
    pv[i] = *(const s16x8*)&P[(row0 + pm + i * 32) * 768L + h * 64 + pt0];

  f32x4 acc[4][4] = {};
  const short* Qh = Q + (long)hi * SLOT;
  auto stage = [&](int b, int kt){
    short* As = smem + b * 16384;
    #pragma unroll
    for(int it = 0; it < 4; ++it){
      int r = it * 32 + w * 8;
      gld_lds16(&Qh[(row0 + r + lr) * 768L + kt + sA], &As[r * 64]);
      gld_lds16(&X[(row0 + r + lr) * 768L + kt + sA], &As[8192 + r * 64]);
    }
  };

  stage(0, 0);
  for(int t = 0; t < 12; ++t){
    const int cur = t & 1;
    if(t < 11){
      stage(cur ^ 1, (t + 1) * 64);
      asm volatile("s_waitcnt vmcnt(8)\n\ts_barrier" ::: "memory");
    } else {
      asm volatile("s_waitcnt vmcnt(0)\n\ts_barrier" ::: "memory");
    }
    const short* As = smem + cur * 16384;
    const short* Bs = As + 8192;
    #pragma unroll
    for(int kk = 0; kk < 2; ++kk){
      s16x8 af[4], bfr[4];
      #pragma unroll
      for(int m = 0; m < 4; ++m){
        int row = wr * 64 + m * 16 + (lane & 15);
        af[m] = *(const s16x8*)&As[row * 64 + swz64(row, kk * 32 + (lane >> 4) * 8)];
      }
      #pragma unroll
      for(int n = 0; n < 4; ++n){
        int row = wc * 64 + n * 16 + (lane & 15);
        bfr[n] = *(const s16x8*)&Bs[row * 64 + swz64(row, kk * 32 + (lane >> 4) * 8)];
      }
      #pragma unroll
      for(int m = 0; m < 4; ++m)
        #pragma unroll
        for(int n = 0; n < 4; ++n)
          acc[m][n] = __builtin_amdgcn_mfma_f32_16x16x32_bf16(af[m], bfr[n], acc[m][n], 0, 0, 0);
    }
    asm volatile("s_barrier" ::: "memory");
  }

  short* Pt = smem;           // [64][128]
  short* Vt = smem + 8192;    // [128][64]
  short* Ss = smem + 16384;   // [128][128]

  #pragma unroll
  for(int m = 0; m < 4; ++m)
    #pragma unroll
    for(int n = 0; n < 4; ++n)
      #pragma unroll
      for(int r = 0; r < 4; ++r){
        int row = wr * 64 + m * 16 + (lane >> 4) * 4 + r;
        int c = wc * 64 + n * 16 + (lane & 15);
        Ss[row * 128 + swz64(row, c)] = f2bf(acc[m][n][r]);
      }
  #pragma unroll
  for(int i = 0; i < 4; ++i)
    #pragma unroll
    for(int j = 0; j < 8; ++j){
      int trow = pt0 + j;
      int mc = pm + i * 32;
      Pt[trow * 128 + swz64(trow, mc)] = pv[i][j];
    }
  __syncthreads();

  f32x4 accv[2][4] = {};
  #pragma unroll
  for(int kk = 0; kk < 4; ++kk){
    s16x8 a2[2], b4[4];
    #pragma unroll
    for(int m = 0; m < 2; ++m){
      int row = w * 32 + m * 16 + (lane & 15);
      a2[m] = *(const s16x8*)&Ss[row * 128 + swz64(row, kk * 32 + (lane >> 4) * 8)];
    }
    #pragma unroll
    for(int n = 0; n < 4; ++n){
      int trow = n * 16 + (lane & 15);
      b4[n] = *(const s16x8*)&Pt[trow * 128 + swz64(trow, kk * 32 + (lane >> 4) * 8)];
    }
    #pragma unroll
    for(int m = 0; m < 2; ++m)
      #pragma unroll
      for(int n = 0; n < 4; ++n)
        accv[m][n] = __builtin_amdgcn_mfma_f32_16x16x32_bf16(a2[m], b4[n], accv[m][n], 0, 0, 0);
  }

  #pragma unroll
  for(int m = 0; m < 2; ++m)
    #pragma unroll
    for(int n = 0; n < 4; ++n)
      #pragma unroll
      for(int r = 0; r < 4; ++r){
        int row = w * 32 + m * 16 + (lane >> 4) * 4 + r;
        int c = n * 16 + (lane & 15);
        Vt[row * 64 + swz64(row, c)] = f2bf(accv[m][n][r]);
      }
  __syncthreads();
  #pragma unroll
  for(int k2 = 0; k2 < 4; ++k2){
    int row = k2 * 32 + (tid >> 3);
    int cl = (tid & 7) * 8;
    s16x8 v = *(const s16x8*)&Vt[row * 64 + swz64(row, cl)];
    *(s16x8*)&Cat[(row0 + row) * 768L + h * 64 + cl] = v;
  }
}

extern "C" void kernel_launch(void* const* d_in, const int* in_sizes, int n_in,
                              void* d_out, int out_size, void* d_ws, size_t ws_size,
                              hipStream_t stream){
  const float* x  = (const float*)d_in[0];
  const float* Wq = (const float*)d_in[1];
  const float* bq = (const float*)d_in[2];
  const float* Wv = (const float*)d_in[3];
  const float* bv = (const float*)d_in[4];
  const float* Wf = (const float*)d_in[5];
  const float* bfv= (const float*)d_in[6];

  const float rsqE = 0.03608439182435161f;  // 1/sqrt(768)
  char* ws = (char*)d_ws;

  short* Xb  = (short*)(ws);
  short* Cat = (short*)(ws + 100663296L);
  short* Wb  = (short*)(ws + 201326592L);   // [13*768][768] bf16
  short* Wfb = (short*)(ws + 216662016L);
  float* bQP = (float*)(ws + 217841664L);   // [9984]
  float* cv  = (float*)(ws + 217881600L);
  short* QS  = (short*)(ws + 217884672L);   // (G+1) slots of [65536][768]

  const size_t QOFF = 217884672ULL;
  int G = 1;
  const int cands[5] = {12, 6, 4, 3, 2};
  for(int i = 0; i < 5; ++i)
    if(ws_size >= QOFF + (size_t)(cands[i] + 1) * 100663296ULL){ G = cands[i]; break; }
  short* Pall = QS + (long)G * SLOT;

  // opt-in to 128 KiB dynamic LDS; fall back to ring-2 BK=32 if unavailable
  bool deep = hipFuncSetAttribute(reinterpret_cast<const void*>(&gemm64),
                  hipFuncAttributeMaxDynamicSharedMemorySize, 131072) == hipSuccess;

  dim3 b256(256), b512(512);
  cast_bf16_k<<<24576, b256, 0, stream>>>(x,  Xb, 50331648L, 1.f);
  cast_bf16_k<<<3456,  b256, 0, stream>>>(Wq, Wb, 7077888L, 1.f);
  cast_bf16_k<<<288,   b256, 0, stream>>>(Wv, Wb + 7077888L, 589824L, rsqE);
  cast_bf16_k<<<288,   b256, 0, stream>>>(Wf, Wfb, 589824L, 1.f);
  bias_build<<<39, b256, 0, stream>>>(bq, bQP);
  cvec_k<<<3, b256, 0, stream>>>(Wf, bv, bfv, cv);

  const int nB = 12 / G;
  for(int b = 0; b < nB; ++b){
    const int nSub = G + (b == 0 ? 1 : 0);
    const int pSub = (b == 0) ? G : -1;
    if(deep)
      gemm64<<<dim3(nSub * 768), b512, 131072, stream>>>(Xb, Wb, bQP, QS, b * G, nSub, pSub);
    else
      gemm256<<<dim3(nSub * 768), b512, 0, stream>>>(Xb, Wb, bQP, QS, b * G, nSub, pSub);
    attn_k<<<dim3(G * 512), b256, 0, stream>>>(QS, Pall, Xb, Cat, b * G, G);
  }
  gemm_f32<<<dim3(3072), b256, 0, stream>>>(Cat, Wfb, cv, (float*)d_out);
}

// Round 10
// 1679.802 us; speedup vs baseline: 1.0989x; 1.0374x over previous
//
#include <hip/hip_runtime.h>
#include <stdint.h>

// SelfAttention: B=64,N=8,L=128,E=768,H=12,T=64  (S=512 sets of 128 tokens)
//
// gemm8p: 256x256 tile, BK=64 (12 K-tiles), 8 waves, ring-2 128KiB dynamic
// LDS, m201-style 4-phase-per-K-tile schedule: per phase {ds_read 4-12 frag
// (quadrant-reuse) ∥ stage 1 half-tile (2 gld_lds) → barrier → lgkmcnt(0) →
// setprio + 16 MFMA → barrier}; ONE counted vmcnt(2) per K-tile (phase 0),
// vmcnt(0) only at the last tile. swz64 LDS (measured 0-conflict), XCD-chunked
// zero-tail grid. Ring-2 BK=32 fallback if dyn-LDS opt-in fails.

#define EE 768
#define SLOT 50331648L   // shorts per [65536][768] slot

typedef short s16x8 __attribute__((ext_vector_type(8)));
typedef float f32x4 __attribute__((ext_vector_type(4)));

__device__ __forceinline__ short f2bf(float f){
  union { float fv; uint32_t u; } v; v.fv = f;
  uint32_t r = (v.u + 0x7fffu + ((v.u >> 16) & 1u)) >> 16;  // RNE
  return (short)r;
}

__device__ __forceinline__ void gld_lds16(const short* g, short* l){
  __builtin_amdgcn_global_load_lds(
      (const __attribute__((address_space(1))) void*)(uintptr_t)g,
      (__attribute__((address_space(3))) void*)(uintptr_t)l,
      16, 0, 0);
}

// bijective XCD chunking (m204)
__device__ __forceinline__ int xcd_swz(int bid, int nwg){
  int xcd = bid & 7, loc = bid >> 3;
  int q = nwg >> 3, r = nwg & 7;
  return (xcd < r ? xcd * (q + 1) : r * (q + 1) + (xcd - r) * q) + loc;
}

// swizzles (involutions)
__device__ __forceinline__ int swz64(int row, int c){ return c ^ ((row & 7) << 3); }
__device__ __forceinline__ int swz32(int row, int c){ return c ^ (((row >> 1) & 3) << 3); }

// ---------------- casts / small helpers ----------------
__global__ __launch_bounds__(256) void cast_bf16_k(const float* __restrict__ src,
                                                   short* __restrict__ dst,
                                                   long n, float scale){
  long i = ((long)blockIdx.x * 256 + threadIdx.x) * 8;
  if(i >= n) return;
  float4 a = *(const float4*)(src + i);
  float4 b = *(const float4*)(src + i + 4);
  s16x8 o;
  o[0]=f2bf(a.x*scale); o[1]=f2bf(a.y*scale); o[2]=f2bf(a.z*scale); o[3]=f2bf(a.w*scale);
  o[4]=f2bf(b.x*scale); o[5]=f2bf(b.y*scale); o[6]=f2bf(b.z*scale); o[7]=f2bf(b.w*scale);
  *(s16x8*)(dst + i) = o;
}

__global__ __launch_bounds__(256) void cvec_k(const float* __restrict__ Wf,
                                              const float* __restrict__ bv,
                                              const float* __restrict__ bfv,
                                              float* __restrict__ c){
  int e = blockIdx.x * 256 + threadIdx.x;
  if(e >= EE) return;
  float s = bfv[e];
  for(int k = 0; k < EE; ++k) s += Wf[(long)e * EE + k] * bv[k];
  c[e] = s;
}

__global__ __launch_bounds__(256) void bias_build(const float* __restrict__ bq,
                                                  float* __restrict__ biasQP){
  int i = blockIdx.x * 256 + threadIdx.x;
  if(i < 9984) biasQP[i] = (i < 9216) ? bq[i] : 0.f;
}

// ============ 4-phase 256² GEMM, BK=64, ring-2 (dynamic 128 KiB LDS) ============
// Out[g] = A @ W[wh]^T + bias[wh];  K=768 = 12 K-tiles of 64.
__global__ __launch_bounds__(512, 1) void gemm8p(const short* __restrict__ A,
                                                 const short* __restrict__ W,
                                                 const float* __restrict__ bias,
                                                 short* __restrict__ OutBase,
                                                 int hBase, int nSub, int pSub){
  extern __shared__ short lds[];   // 2 bufs × (A 16384 | B 16384 shorts)
  const int tid = threadIdx.x, lane = tid & 63, w = tid >> 6;
  const int wr = w >> 2, wc = w & 3;           // 2x4 wave grid; wave owns 128x64
  const int bid = xcd_swz(blockIdx.x, nSub * 768);
  const int g = bid / 768, rb = bid - g * 768;
  const int rowBlk = rb / 3, colBlk = rb - rowBlk * 3;
  const long rowA0 = (long)rowBlk * 256;
  const int colB0 = colBlk * 256;
  const int wh = (g == pSub) ? 12 : hBase + g;
  const short* Bm = W + (long)wh * 589824L;

  // staging geometry (proven r9): thread covers row j*64 + tid>>3, colseg (tid&7)*8
  const int srow = tid >> 3;                    // 0..63
  const int ssw = swz64(srow, (tid & 7) * 8);   // pre-swizzled source col
  const short* gA = A + (rowA0 + srow) * 768 + ssw;
  const short* gB = Bm + (long)(colB0 + srow) * 768 + ssw;

  // stage one half-tile (128 rows = 2 gld_lds): which 0=A0,1=A1,2=B0,3=B1
  auto stageH = [&](int b, int kt, int which){
    const short* gs = (which < 2 ? gA : gB) + (long)(which & 1) * 98304 + kt;
    short* dst = lds + b * 32768 + (which >> 1) * 16384 + (which & 1) * 8192 + w * 512;
    gld_lds16(gs, dst);
    gld_lds16(gs + 49152, dst + 4096);
  };

  f32x4 acc[8][4] = {};
  const int fr = lane & 15, fcb = (lane >> 4) * 8;
  s16x8 af[4][2], bf[2][2];

  auto readA = [&](int b, int mh){
    const short* Al = lds + b * 32768;
    #pragma unroll
    for(int m = 0; m < 4; ++m){
      int row = wr * 128 + (mh * 4 + m) * 16 + fr;
      #pragma unroll
      for(int kk = 0; kk < 2; ++kk)
        af[m][kk] = *(const s16x8*)&Al[row * 64 + swz64(row, kk * 32 + fcb)];
    }
  };
  auto readB = [&](int b, int nh){
    const short* Bl = lds + b * 32768 + 16384;
    #pragma unroll
    for(int n = 0; n < 2; ++n){
      int row = wc * 64 + (nh * 2 + n) * 16 + fr;
      #pragma unroll
      for(int kk = 0; kk < 2; ++kk)
        bf[n][kk] = *(const s16x8*)&Bl[row * 64 + swz64(row, kk * 32 + fcb)];
    }
  };
  auto mmq = [&](int mh, int nh){
    asm volatile("s_waitcnt lgkmcnt(0)" ::: "memory");
    __builtin_amdgcn_s_setprio(1);
    #pragma unroll
    for(int m = 0; m < 4; ++m)
      #pragma unroll
      for(int n = 0; n < 2; ++n)
        #pragma unroll
        for(int kk = 0; kk < 2; ++kk)
          acc[mh*4+m][nh*2+n] = __builtin_amdgcn_mfma_f32_16x16x32_bf16(
              af[m][kk], bf[n][kk], acc[mh*4+m][nh*2+n], 0, 0, 0);
    __builtin_amdgcn_s_setprio(0);
  };

  // prologue: stage all 4 halves of K-tile 0
  stageH(0, 0, 0); stageH(0, 0, 1); stageH(0, 0, 2); stageH(0, 0, 3);

  for(int t = 0; t < 12; ++t){
    const int b = t & 1, nb = b ^ 1;
    const int kt1 = (t + 1) * 64;
    // ---- phase 0: quadrant (0,0); validate tile t, stage t+1.A0 ----
    if(t < 11){
      stageH(nb, kt1, 0);
      asm volatile("s_waitcnt vmcnt(2)" ::: "memory");  // all of tile t landed
    } else {
      asm volatile("s_waitcnt vmcnt(0)" ::: "memory");
    }
    asm volatile("s_barrier" ::: "memory");
    readA(b, 0); readB(b, 0);
    mmq(0, 0);
    asm volatile("s_barrier" ::: "memory");
    // ---- phase 1: quadrant (0,1); reuse A(mh0), load B(nh1); stage t+1.A1 ----
    readB(b, 1);
    if(t < 11) stageH(nb, kt1, 1);
    asm volatile("s_barrier" ::: "memory");
    mmq(0, 1);
    asm volatile("s_barrier" ::: "memory");
    // ---- phase 2: quadrant (1,1); reuse B(nh1), load A(mh1); stage t+1.B0 ----
    readA(b, 1);
    if(t < 11) stageH(nb, kt1, 2);
    asm volatile("s_barrier" ::: "memory");
    mmq(1, 1);
    asm volatile("s_barrier" ::: "memory");
    // ---- phase 3: quadrant (1,0); reuse A(mh1), load B(nh0); stage t+1.B1 ----
    readB(b, 0);
    if(t < 11) stageH(nb, kt1, 3);
    asm volatile("s_barrier" ::: "memory");
    mmq(1, 0);
    asm volatile("s_barrier" ::: "memory");
  }

  asm volatile("s_waitcnt vmcnt(0) lgkmcnt(0)" ::: "memory");
  __syncthreads();

  float bb[4];
  #pragma unroll
  for(int n = 0; n < 4; ++n)
    bb[n] = bias[wh * 768 + colB0 + wc * 64 + n * 16 + fr];

  short* Out = OutBase + (long)g * SLOT;
  short* Cs = lds;  // [128][256] overlay on dead staging
  #pragma unroll
  for(int ch = 0; ch < 2; ++ch){
    __syncthreads();
    if(wr == ch){
      #pragma unroll
      for(int m = 0; m < 8; ++m)
        #pragma unroll
        for(int n = 0; n < 4; ++n)
          #pragma unroll
          for(int r2 = 0; r2 < 4; ++r2){
            int row = m * 16 + (lane >> 4) * 4 + r2;
            int c = wc * 64 + n * 16 + fr;
            Cs[row * 256 + (c ^ (((row >> 2) & 3) << 4))] = f2bf(acc[m][n][r2] + bb[n]);
          }
    }
    __syncthreads();
    #pragma unroll
    for(int i = 0; i < 8; ++i){
      int idx = i * 512 + tid;
      int row = idx >> 5, cl = (idx & 31) * 8;
      s16x8 v = *(const s16x8*)&Cs[row * 256 + (cl ^ (((row >> 2) & 3) << 4))];
      *(s16x8*)&Out[(rowA0 + ch * 128 + row) * 768 + colB0 + cl] = v;
    }
  }
}

// ============ FALLBACK: proven round-4 ring-2 BK=32 kernel ============
__global__ __launch_bounds__(512, 1) void gemm256(const short* __restrict__ A,
                                                  const short* __restrict__ W,
                                                  const float* __restrict__ bias,
                                                  short* __restrict__ OutBase,
                                                  int hBase, int nSub, int pSub){
  __shared__ short lds[2][16384];
  const int tid = threadIdx.x, lane = tid & 63, w = tid >> 6;
  const int wr = w >> 2, wc = w & 3;
  const int bid = xcd_swz(blockIdx.x, nSub * 768);
  const int g = bid / 768, rb = bid - g * 768;
  const int rowBlk = rb / 3, colBlk = rb - rowBlk * 3;
  const long rowA0 = (long)rowBlk * 256;
  const int colB0 = colBlk * 256;
  const int wh = (g == pSub) ? 12 : hBase + g;
  const short* Bm = W + (long)wh * 589824L;
  short* Out = OutBase + (long)g * SLOT;

  const int sr0 = w * 32 + (lane >> 2);
  const int sr1 = sr0 + 16;
  const int scol = (lane & 3) * 8;
  const int sc0 = swz32(sr0, scol);
  const int sc1 = swz32(sr1, scol);
  const short* Ar0 = A + (rowA0 + sr0) * 768;
  const short* Ar1 = A + (rowA0 + sr1) * 768;
  const short* Br0 = Bm + (long)(colB0 + sr0) * 768;
  const short* Br1 = Bm + (long)(colB0 + sr1) * 768;

  f32x4 acc[8][4] = {};
  s16x8 af[4], bf0[2], bf1[2];
  const int fr = lane & 15, fc = (lane >> 4) * 8;

  auto stage = [&](int b, int kt){
    short* Al = &lds[b][0];
    short* Bl = &lds[b][8192];
    gld_lds16(Ar0 + kt + sc0, Al + (w * 2) * 512);
    gld_lds16(Ar1 + kt + sc1, Al + (w * 2 + 1) * 512);
    gld_lds16(Br0 + kt + sc0, Bl + (w * 2) * 512);
    gld_lds16(Br1 + kt + sc1, Bl + (w * 2 + 1) * 512);
  };

  stage(0, 0);
  for(int t = 0; t < 24; ++t){
    if(t < 23){
      stage((t + 1) & 1, (t + 1) * 32);
      asm volatile("s_waitcnt vmcnt(4)\n\ts_barrier" ::: "memory");
    } else {
      asm volatile("s_waitcnt vmcnt(0)\n\ts_barrier" ::: "memory");
    }
    const short* Al = &lds[t & 1][0];
    const short* Bl = &lds[t & 1][8192];

    auto loadA = [&](int mh){
      #pragma unroll
      for(int m = 0; m < 4; ++m){
        int row = wr * 128 + (mh * 4 + m) * 16 + fr;
        af[m] = *(const s16x8*)&Al[row * 32 + swz32(row, fc)];
      }
    };
    auto loadB = [&](int nh, s16x8* bf){
      #pragma unroll
      for(int n = 0; n < 2; ++n){
        int row = wc * 64 + (nh * 2 + n) * 16 + fr;
        bf[n] = *(const s16x8*)&Bl[row * 32 + swz32(row, fc)];
      }
    };
    auto mm = [&](int mh, int nh, s16x8* bf){
      __builtin_amdgcn_s_setprio(1);
      #pragma unroll
      for(int m = 0; m < 4; ++m)
        #pragma unroll
        for(int n = 0; n < 2; ++n)
          acc[mh * 4 + m][nh * 2 + n] = __builtin_amdgcn_mfma_f32_16x16x32_bf16(
              af[m], bf[n], acc[mh * 4 + m][nh * 2 + n], 0, 0, 0);
      __builtin_amdgcn_s_setprio(0);
    };

    loadA(0); loadB(0, bf0); mm(0, 0, bf0);
    loadB(1, bf1);           mm(0, 1, bf1);
    loadA(1);                mm(1, 1, bf1);
    loadB(0, bf0);           mm(1, 0, bf0);
    asm volatile("s_barrier" ::: "memory");
  }

  float bb[4];
  #pragma unroll
  for(int n = 0; n < 4; ++n)
    bb[n] = bias[wh * 768 + colB0 + wc * 64 + n * 16 + fr];

  short* Cs = &lds[0][0];
  #pragma unroll
  for(int ch = 0; ch < 2; ++ch){
    __syncthreads();
    if(wr == ch){
      #pragma unroll
      for(int m = 0; m < 8; ++m)
        #pragma unroll
        for(int n = 0; n < 4; ++n)
          #pragma unroll
          for(int r2 = 0; r2 < 4; ++r2){
            int row = m * 16 + (lane >> 4) * 4 + r2;
            int c = wc * 64 + n * 16 + fr;
            Cs[row * 256 + (c ^ (((row >> 2) & 3) << 4))] = f2bf(acc[m][n][r2] + bb[n]);
          }
    }
    __syncthreads();
    #pragma unroll
    for(int i = 0; i < 8; ++i){
      int idx = i * 512 + tid;
      int row = idx >> 5, cl = (idx & 31) * 8;
      s16x8 v = *(const s16x8*)&Cs[row * 256 + (cl ^ (((row >> 2) & 3) << 4))];
      *(s16x8*)&Out[(rowA0 + ch * 128 + row) * 768 + colB0 + cl] = v;
    }
  }
}

// ------ final C[M,768] = A @ B^T + bias (fp32 out); 128² 2-phase (proven) ------
__global__ __launch_bounds__(256, 2) void gemm_f32(const short* __restrict__ A,
                                                   const short* __restrict__ B,
                                                   const float* __restrict__ bias,
                                                   float* __restrict__ Cout){
  __shared__ short smem[4 * 8192];
  const int tid = threadIdx.x, lane = tid & 63, w = tid >> 6;
  const int wr = w >> 1, wc = w & 1;
  const int nCol = 6;
  const int xcd = blockIdx.x & 7, loc = blockIdx.x >> 3;
  const int width = nCol << 3;
  const int gid = loc / width, rem = loc % width;
  const int rowBlk = (xcd << 6) + (gid << 3) + (rem & 7);
  const int colBlk = rem >> 3;
  const long rowA0 = (long)rowBlk << 7;
  const long colB0 = (long)colBlk << 7;
  const int lr = lane >> 3;
  const int sA = swz64(lr, (lane & 7) * 8);

  f32x4 acc[4][4] = {};
  auto stage = [&](int b, int kt){
    short* As = smem + b * 16384;
    #pragma unroll
    for(int it = 0; it < 4; ++it){
      int r = it * 32 + w * 8;
      gld_lds16(&A[(rowA0 + r + lr) * 768 + kt + sA], &As[r * 64]);
      gld_lds16(&B[(colB0 + r + lr) * 768 + kt + sA], &As[8192 + r * 64]);
    }
  };

  stage(0, 0);
  for(int t = 0; t < 12; ++t){
    const int cur = t & 1;
    if(t < 11){
      stage(cur ^ 1, (t + 1) * 64);
      asm volatile("s_waitcnt vmcnt(8)\n\ts_barrier" ::: "memory");
    } else {
      asm volatile("s_waitcnt vmcnt(0)\n\ts_barrier" ::: "memory");
    }
    const short* As = smem + cur * 16384;
    const short* Bs = As + 8192;
    #pragma unroll
    for(int kk = 0; kk < 2; ++kk){
      s16x8 af[4], bfr[4];
      #pragma unroll
      for(int m = 0; m < 4; ++m){
        int row = wr * 64 + m * 16 + (lane & 15);
        af[m] = *(const s16x8*)&As[row * 64 + swz64(row, kk * 32 + (lane >> 4) * 8)];
      }
      #pragma unroll
      for(int n = 0; n < 4; ++n){
        int row = wc * 64 + n * 16 + (lane & 15);
        bfr[n] = *(const s16x8*)&Bs[row * 64 + swz64(row, kk * 32 + (lane >> 4) * 8)];
      }
      #pragma unroll
      for(int m = 0; m < 4; ++m)
        #pragma unroll
        for(int n = 0; n < 4; ++n)
          acc[m][n] = __builtin_amdgcn_mfma_f32_16x16x32_bf16(af[m], bfr[n], acc[m][n], 0, 0, 0);
    }
    asm volatile("s_barrier" ::: "memory");
  }

  const long crow0 = rowA0 + wr * 64;
  const long ccol0 = colB0 + wc * 64;
  #pragma unroll
  for(int n = 0; n < 4; ++n){
    const long col = ccol0 + n * 16 + (lane & 15);
    const float bbv = bias[col];
    #pragma unroll
    for(int m = 0; m < 4; ++m)
      #pragma unroll
      for(int r = 0; r < 4; ++r){
        const long row = crow0 + m * 16 + (lane >> 4) * 4 + r;
        Cout[row * 768 + col] = acc[m][n][r] + bbv;
      }
  }
}

// ------ fused per-(h,s): scores = Q@Xs^T ; V' = scores@P ; -> Cat -----------
__global__ __launch_bounds__(256, 2) void attn_k(const short* __restrict__ Q,
                                                 const short* __restrict__ P,
                                                 const short* __restrict__ X,
                                                 short* __restrict__ Cat,
                                                 int h0, int nH){
  __shared__ short smem[4 * 8192];
  const int tid = threadIdx.x, lane = tid & 63, w = tid >> 6;
  const int wr = w >> 1, wc = w & 1;
  const int nwg = nH << 9;
  const int bid = xcd_swz(blockIdx.x, nwg);
  const int s = bid / nH, hi = bid - s * nH, h = h0 + hi;
  const long row0 = (long)s * 128;
  const int lr = lane >> 3;
  const int sA = swz64(lr, (lane & 7) * 8);

  const int pm = tid >> 3, pt0 = (tid & 7) * 8;
  s16x8 pv[4];
  #pragma unroll
  for(int i = 0; i < 4; ++i)
    pv[i] = *(const s16x8*)&P[(row0 + pm + i * 32) * 768L + h * 64 + pt0];

  f32x4 acc[4][4] = {};
  const short* Qh = Q + (long)hi * SLOT;
  auto stage = [&](int b, int kt){
    short* As = smem + b * 16384;
    #pragma unroll
    for(int it = 0; it < 4; ++it){
      int r = it * 32 + w * 8;
      gld_lds16(&Qh[(row0 + r + lr) * 768L + kt + sA], &As[r * 64]);
      gld_lds16(&X[(row0 + r + lr) * 768L + kt + sA], &As[8192 + r * 64]);
    }
  };

  stage(0, 0);
  for(int t = 0; t < 12; ++t){
    const int cur = t & 1;
    if(t < 11){
      stage(cur ^ 1, (t + 1) * 64);
      asm volatile("s_waitcnt vmcnt(8)\n\ts_barrier" ::: "memory");
    } else {
      asm volatile("s_waitcnt vmcnt(0)\n\ts_barrier" ::: "memory");
    }
    const short* As = smem + cur * 16384;
    const short* Bs = As + 8192;
    #pragma unroll
    for(int kk = 0; kk < 2; ++kk){
      s16x8 af[4], bfr[4];
      #pragma unroll
      for(int m = 0; m < 4; ++m){
        int row = wr * 64 + m * 16 + (lane & 15);
        af[m] = *(const s16x8*)&As[row * 64 + swz64(row, kk * 32 + (lane >> 4) * 8)];
      }
      #pragma unroll
      for(int n = 0; n < 4; ++n){
        int row = wc * 64 + n * 16 + (lane & 15);
        bfr[n] = *(const s16x8*)&Bs[row * 64 + swz64(row, kk * 32 + (lane >> 4) * 8)];
      }
      #pragma unroll
      for(int m = 0; m < 4; ++m)
        #pragma unroll
        for(int n = 0; n < 4; ++n)
          acc[m][n] = __builtin_amdgcn_mfma_f32_16x16x32_bf16(af[m], bfr[n], acc[m][n], 0, 0, 0);
    }
    asm volatile("s_barrier" ::: "memory");
  }

  short* Pt = smem;           // [64][128]
  short* Vt = smem + 8192;    // [128][64]
  short* Ss = smem + 16384;   // [128][128]

  #pragma unroll
  for(int m = 0; m < 4; ++m)
    #pragma unroll
    for(int n = 0; n < 4; ++n)
      #pragma unroll
      for(int r = 0; r < 4; ++r){
        int row = wr * 64 + m * 16 + (lane >> 4) * 4 + r;
        int c = wc * 64 + n * 16 + (lane & 15);
        Ss[row * 128 + swz64(row, c)] = f2bf(acc[m][n][r]);
      }
  #pragma unroll
  for(int i = 0; i < 4; ++i)
    #pragma unroll
    for(int j = 0; j < 8; ++j){
      int trow = pt0 + j;
      int mc = pm + i * 32;
      Pt[trow * 128 + swz64(trow, mc)] = pv[i][j];
    }
  __syncthreads();

  f32x4 accv[2][4] = {};
  #pragma unroll
  for(int kk = 0; kk < 4; ++kk){
    s16x8 a2[2], b4[4];
    #pragma unroll
    for(int m = 0; m < 2; ++m){
      int row = w * 32 + m * 16 + (lane & 15);
      a2[m] = *(const s16x8*)&Ss[row * 128 + swz64(row, kk * 32 + (lane >> 4) * 8)];
    }
    #pragma unroll
    for(int n = 0; n < 4; ++n){
      int trow = n * 16 + (lane & 15);
      b4[n] = *(const s16x8*)&Pt[trow * 128 + swz64(trow, kk * 32 + (lane >> 4) * 8)];
    }
    #pragma unroll
    for(int m = 0; m < 2; ++m)
      #pragma unroll
      for(int n = 0; n < 4; ++n)
        accv[m][n] = __builtin_amdgcn_mfma_f32_16x16x32_bf16(a2[m], b4[n], accv[m][n], 0, 0, 0);
  }

  #pragma unroll
  for(int m = 0; m < 2; ++m)
    #pragma unroll
    for(int n = 0; n < 4; ++n)
      #pragma unroll
      for(int r = 0; r < 4; ++r){
        int row = w * 32 + m * 16 + (lane >> 4) * 4 + r;
        int c = n * 16 + (lane & 15);
        Vt[row * 64 + swz64(row, c)] = f2bf(accv[m][n][r]);
      }
  __syncthreads();
  #pragma unroll
  for(int k2 = 0; k2 < 4; ++k2){
    int row = k2 * 32 + (tid >> 3);
    int cl = (tid & 7) * 8;
    s16x8 v = *(const s16x8*)&Vt[row * 64 + swz64(row, cl)];
    *(s16x8*)&Cat[(row0 + row) * 768L + h * 64 + cl] = v;
  }
}

extern "C" void kernel_launch(void* const* d_in, const int* in_sizes, int n_in,
                              void* d_out, int out_size, void* d_ws, size_t ws_size,
                              hipStream_t stream){
  const float* x  = (const float*)d_in[0];
  const float* Wq = (const float*)d_in[1];
  const float* bq = (const float*)d_in[2];
  const float* Wv = (const float*)d_in[3];
  const float* bv = (const float*)d_in[4];
  const float* Wf = (const float*)d_in[5];
  const float* bfv= (const float*)d_in[6];

  const float rsqE = 0.03608439182435161f;  // 1/sqrt(768)
  char* ws = (char*)d_ws;

  short* Xb  = (short*)(ws);
  short* Cat = (short*)(ws + 100663296L);
  short* Wb  = (short*)(ws + 201326592L);   // [13*768][768] bf16
  short* Wfb = (short*)(ws + 216662016L);
  float* bQP = (float*)(ws + 217841664L);   // [9984]
  float* cv  = (float*)(ws + 217881600L);
  short* QS  = (short*)(ws + 217884672L);   // (G+1) slots of [65536][768]

  const size_t QOFF = 217884672ULL;
  int G = 1;
  const int cands[5] = {12, 6, 4, 3, 2};
  for(int i = 0; i < 5; ++i)
    if(ws_size >= QOFF + (size_t)(cands[i] + 1) * 100663296ULL){ G = cands[i]; break; }
  short* Pall = QS + (long)G * SLOT;

  // opt-in to 128 KiB dynamic LDS; fall back to ring-2 BK=32 if unavailable
  bool deep = hipFuncSetAttribute(reinterpret_cast<const void*>(&gemm8p),
                  hipFuncAttributeMaxDynamicSharedMemorySize, 131072) == hipSuccess;

  dim3 b256(256), b512(512);
  cast_bf16_k<<<24576, b256, 0, stream>>>(x,  Xb, 50331648L, 1.f);
  cast_bf16_k<<<3456,  b256, 0, stream>>>(Wq, Wb, 7077888L, 1.f);
  cast_bf16_k<<<288,   b256, 0, stream>>>(Wv, Wb + 7077888L, 589824L, rsqE);
  cast_bf16_k<<<288,   b256, 0, stream>>>(Wf, Wfb, 589824L, 1.f);
  bias_build<<<39, b256, 0, stream>>>(bq, bQP);
  cvec_k<<<3, b256, 0, stream>>>(Wf, bv, bfv, cv);

  const int nB = 12 / G;
  for(int b = 0; b < nB; ++b){
    const int nSub = G + (b == 0 ? 1 : 0);
    const int pSub = (b == 0) ? G : -1;
    if(deep)
      gemm8p<<<dim3(nSub * 768), b512, 131072, stream>>>(Xb, Wb, bQP, QS, b * G, nSub, pSub);
    else
      gemm256<<<dim3(nSub * 768), b512, 0, stream>>>(Xb, Wb, bQP, QS, b * G, nSub, pSub);
    attn_k<<<dim3(G * 512), b256, 0, stream>>>(QS, Pall, Xb, Cat, b * G, G);
  }
  gemm_f32<<<dim3(3072), b256, 0, stream>>>(Cat, Wfb, cv, (float*)d_out);
}

// Round 11
// 1671.177 us; speedup vs baseline: 1.1046x; 1.0052x over previous
//
#include <hip/hip_runtime.h>
#include <stdint.h>

// SelfAttention: B=64,N=8,L=128,E=768,H=12,T=64  (S=512 sets of 128 tokens)
//
// gemm8p<OUTF32>: 256x256 tile, BK=64 (12 K-tiles), 8 waves, ring-2 128KiB
// dynamic LDS, 4-phase-per-K-tile quadrant schedule (r10-proven, 920 TF):
// per phase {ds_read frags (quadrant reuse) ∥ stage 1 half-tile → barrier →
// lgkmcnt(0) → setprio + 16 MFMA → barrier}; ONE counted vmcnt(2)/K-tile.
// attn_k: same phase structure scaled to 4 waves for QK^T, then in-LDS PV.
// swz64 LDS (0-conflict), XCD-chunked zero-tail grids.

#define EE 768
#define SLOT 50331648L   // shorts per [65536][768] slot

typedef short s16x8 __attribute__((ext_vector_type(8)));
typedef float f32x4 __attribute__((ext_vector_type(4)));

__device__ __forceinline__ short f2bf(float f){
  union { float fv; uint32_t u; } v; v.fv = f;
  uint32_t r = (v.u + 0x7fffu + ((v.u >> 16) & 1u)) >> 16;  // RNE
  return (short)r;
}

__device__ __forceinline__ void gld_lds16(const short* g, short* l){
  __builtin_amdgcn_global_load_lds(
      (const __attribute__((address_space(1))) void*)(uintptr_t)g,
      (__attribute__((address_space(3))) void*)(uintptr_t)l,
      16, 0, 0);
}

// bijective XCD chunking (m204)
__device__ __forceinline__ int xcd_swz(int bid, int nwg){
  int xcd = bid & 7, loc = bid >> 3;
  int q = nwg >> 3, r = nwg & 7;
  return (xcd < r ? xcd * (q + 1) : r * (q + 1) + (xcd - r) * q) + loc;
}

// swizzles (involutions)
__device__ __forceinline__ int swz64(int row, int c){ return c ^ ((row & 7) << 3); }
__device__ __forceinline__ int swz32(int row, int c){ return c ^ (((row >> 1) & 3) << 3); }

// ---------------- casts / small helpers ----------------
__global__ __launch_bounds__(256) void cast_bf16_k(const float* __restrict__ src,
                                                   short* __restrict__ dst,
                                                   long n, float scale){
  long i = ((long)blockIdx.x * 256 + threadIdx.x) * 8;
  if(i >= n) return;
  float4 a = *(const float4*)(src + i);
  float4 b = *(const float4*)(src + i + 4);
  s16x8 o;
  o[0]=f2bf(a.x*scale); o[1]=f2bf(a.y*scale); o[2]=f2bf(a.z*scale); o[3]=f2bf(a.w*scale);
  o[4]=f2bf(b.x*scale); o[5]=f2bf(b.y*scale); o[6]=f2bf(b.z*scale); o[7]=f2bf(b.w*scale);
  *(s16x8*)(dst + i) = o;
}

__global__ __launch_bounds__(256) void cvec_k(const float* __restrict__ Wf,
                                              const float* __restrict__ bv,
                                              const float* __restrict__ bfv,
                                              float* __restrict__ c){
  int e = blockIdx.x * 256 + threadIdx.x;
  if(e >= EE) return;
  float s = bfv[e];
  for(int k = 0; k < EE; ++k) s += Wf[(long)e * EE + k] * bv[k];
  c[e] = s;
}

__global__ __launch_bounds__(256) void bias_build(const float* __restrict__ bq,
                                                  float* __restrict__ biasQP){
  int i = blockIdx.x * 256 + threadIdx.x;
  if(i < 9984) biasQP[i] = (i < 9216) ? bq[i] : 0.f;
}

// ============ 4-phase 256² GEMM, BK=64, ring-2 (dynamic 128 KiB LDS) ============
// Out[g] = A @ W[wh]^T + bias[wh];  K=768 = 12 K-tiles of 64.
template<bool OUTF32>
__global__ __launch_bounds__(512, 1) void gemm8p(const short* __restrict__ A,
                                                 const short* __restrict__ W,
                                                 const float* __restrict__ bias,
                                                 void* __restrict__ OutBase,
                                                 int hBase, int nSub, int pSub){
  extern __shared__ short lds[];   // 2 bufs × (A 16384 | B 16384 shorts)
  const int tid = threadIdx.x, lane = tid & 63, w = tid >> 6;
  const int wr = w >> 2, wc = w & 3;           // 2x4 wave grid; wave owns 128x64
  const int bid = xcd_swz(blockIdx.x, nSub * 768);
  const int g = bid / 768, rb = bid - g * 768;
  const int rowBlk = rb / 3, colBlk = rb - rowBlk * 3;
  const long rowA0 = (long)rowBlk * 256;
  const int colB0 = colBlk * 256;
  const int wh = (g == pSub) ? 12 : hBase + g;
  const short* Bm = W + (long)wh * 589824L;

  const int srow = tid >> 3;                    // 0..63
  const int ssw = swz64(srow, (tid & 7) * 8);   // pre-swizzled source col
  const short* gA = A + (rowA0 + srow) * 768 + ssw;
  const short* gB = Bm + (long)(colB0 + srow) * 768 + ssw;

  // stage one half-tile (128 rows = 2 gld_lds): which 0=A0,1=A1,2=B0,3=B1
  auto stageH = [&](int b, int kt, int which){
    const short* gs = (which < 2 ? gA : gB) + (long)(which & 1) * 98304 + kt;
    short* dst = lds + b * 32768 + (which >> 1) * 16384 + (which & 1) * 8192 + w * 512;
    gld_lds16(gs, dst);
    gld_lds16(gs + 49152, dst + 4096);
  };

  f32x4 acc[8][4] = {};
  const int fr = lane & 15, fcb = (lane >> 4) * 8;
  s16x8 af[4][2], bf[2][2];

  auto readA = [&](int b, int mh){
    const short* Al = lds + b * 32768;
    #pragma unroll
    for(int m = 0; m < 4; ++m){
      int row = wr * 128 + (mh * 4 + m) * 16 + fr;
      #pragma unroll
      for(int kk = 0; kk < 2; ++kk)
        af[m][kk] = *(const s16x8*)&Al[row * 64 + swz64(row, kk * 32 + fcb)];
    }
  };
  auto readB = [&](int b, int nh){
    const short* Bl = lds + b * 32768 + 16384;
    #pragma unroll
    for(int n = 0; n < 2; ++n){
      int row = wc * 64 + (nh * 2 + n) * 16 + fr;
      #pragma unroll
      for(int kk = 0; kk < 2; ++kk)
        bf[n][kk] = *(const s16x8*)&Bl[row * 64 + swz64(row, kk * 32 + fcb)];
    }
  };
  auto mmq = [&](int mh, int nh){
    asm volatile("s_waitcnt lgkmcnt(0)" ::: "memory");
    __builtin_amdgcn_s_setprio(1);
    #pragma unroll
    for(int m = 0; m < 4; ++m)
      #pragma unroll
      for(int n = 0; n < 2; ++n)
        #pragma unroll
        for(int kk = 0; kk < 2; ++kk)
          acc[mh*4+m][nh*2+n] = __builtin_amdgcn_mfma_f32_16x16x32_bf16(
              af[m][kk], bf[n][kk], acc[mh*4+m][nh*2+n], 0, 0, 0);
    __builtin_amdgcn_s_setprio(0);
  };

  // prologue: stage all 4 halves of K-tile 0
  stageH(0, 0, 0); stageH(0, 0, 1); stageH(0, 0, 2); stageH(0, 0, 3);

  for(int t = 0; t < 12; ++t){
    const int b = t & 1, nb = b ^ 1;
    const int kt1 = (t + 1) * 64;
    if(t < 11){
      stageH(nb, kt1, 0);
      asm volatile("s_waitcnt vmcnt(2)" ::: "memory");
    } else {
      asm volatile("s_waitcnt vmcnt(0)" ::: "memory");
    }
    asm volatile("s_barrier" ::: "memory");
    readA(b, 0); readB(b, 0);
    mmq(0, 0);
    asm volatile("s_barrier" ::: "memory");
    readB(b, 1);
    if(t < 11) stageH(nb, kt1, 1);
    asm volatile("s_barrier" ::: "memory");
    mmq(0, 1);
    asm volatile("s_barrier" ::: "memory");
    readA(b, 1);
    if(t < 11) stageH(nb, kt1, 2);
    asm volatile("s_barrier" ::: "memory");
    mmq(1, 1);
    asm volatile("s_barrier" ::: "memory");
    readB(b, 0);
    if(t < 11) stageH(nb, kt1, 3);
    asm volatile("s_barrier" ::: "memory");
    mmq(1, 0);
    asm volatile("s_barrier" ::: "memory");
  }

  asm volatile("s_waitcnt vmcnt(0) lgkmcnt(0)" ::: "memory");
  __syncthreads();

  float bb[4];
  #pragma unroll
  for(int n = 0; n < 4; ++n)
    bb[n] = bias[wh * 768 + colB0 + wc * 64 + n * 16 + fr];

  if constexpr(!OUTF32){
    short* Out = (short*)OutBase + (long)g * SLOT;
    short* Cs = lds;  // [128][256] overlay on dead staging
    #pragma unroll
    for(int ch = 0; ch < 2; ++ch){
      __syncthreads();
      if(wr == ch){
        #pragma unroll
        for(int m = 0; m < 8; ++m)
          #pragma unroll
          for(int n = 0; n < 4; ++n)
            #pragma unroll
            for(int r2 = 0; r2 < 4; ++r2){
              int row = m * 16 + (lane >> 4) * 4 + r2;
              int c = wc * 64 + n * 16 + fr;
              Cs[row * 256 + (c ^ (((row >> 2) & 3) << 4))] = f2bf(acc[m][n][r2] + bb[n]);
            }
      }
      __syncthreads();
      #pragma unroll
      for(int i = 0; i < 8; ++i){
        int idx = i * 512 + tid;
        int row = idx >> 5, cl = (idx & 31) * 8;
        s16x8 v = *(const s16x8*)&Cs[row * 256 + (cl ^ (((row >> 2) & 3) << 4))];
        *(s16x8*)&Out[(rowA0 + ch * 128 + row) * 768 + colB0 + cl] = v;
      }
    }
  } else {
    float* Co = (float*)OutBase;
    #pragma unroll
    for(int m = 0; m < 8; ++m)
      #pragma unroll
      for(int n = 0; n < 4; ++n)
        #pragma unroll
        for(int r2 = 0; r2 < 4; ++r2){
          const long row = rowA0 + wr * 128 + m * 16 + (lane >> 4) * 4 + r2;
          const int col = colB0 + wc * 64 + n * 16 + fr;
          Co[row * 768 + col] = acc[m][n][r2] + bb[n];
        }
  }
}

// ============ FALLBACK: proven round-4 ring-2 BK=32 kernel ============
__global__ __launch_bounds__(512, 1) void gemm256(const short* __restrict__ A,
                                                  const short* __restrict__ W,
                                                  const float* __restrict__ bias,
                                                  short* __restrict__ OutBase,
                                                  int hBase, int nSub, int pSub){
  __shared__ short lds[2][16384];
  const int tid = threadIdx.x, lane = tid & 63, w = tid >> 6;
  const int wr = w >> 2, wc = w & 3;
  const int bid = xcd_swz(blockIdx.x, nSub * 768);
  const int g = bid / 768, rb = bid - g * 768;
  const int rowBlk = rb / 3, colBlk = rb - rowBlk * 3;
  const long rowA0 = (long)rowBlk * 256;
  const int colB0 = colBlk * 256;
  const int wh = (g == pSub) ? 12 : hBase + g;
  const short* Bm = W + (long)wh * 589824L;
  short* Out = OutBase + (long)g * SLOT;

  const int sr0 = w * 32 + (lane >> 2);
  const int sr1 = sr0 + 16;
  const int scol = (lane & 3) * 8;
  const int sc0 = swz32(sr0, scol);
  const int sc1 = swz32(sr1, scol);
  const short* Ar0 = A + (rowA0 + sr0) * 768;
  const short* Ar1 = A + (rowA0 + sr1) * 768;
  const short* Br0 = Bm + (long)(colB0 + sr0) * 768;
  const short* Br1 = Bm + (long)(colB0 + sr1) * 768;

  f32x4 acc[8][4] = {};
  s16x8 af[4], bf0[2], bf1[2];
  const int fr = lane & 15, fc = (lane >> 4) * 8;

  auto stage = [&](int b, int kt){
    short* Al = &lds[b][0];
    short* Bl = &lds[b][8192];
    gld_lds16(Ar0 + kt + sc0, Al + (w * 2) * 512);
    gld_lds16(Ar1 + kt + sc1, Al + (w * 2 + 1) * 512);
    gld_lds16(Br0 + kt + sc0, Bl + (w * 2) * 512);
    gld_lds16(Br1 + kt + sc1, Bl + (w * 2 + 1) * 512);
  };

  stage(0, 0);
  for(int t = 0; t < 24; ++t){
    if(t < 23){
      stage((t + 1) & 1, (t + 1) * 32);
      asm volatile("s_waitcnt vmcnt(4)\n\ts_barrier" ::: "memory");
    } else {
      asm volatile("s_waitcnt vmcnt(0)\n\ts_barrier" ::: "memory");
    }
    const short* Al = &lds[t & 1][0];
    const short* Bl = &lds[t & 1][8192];

    auto loadA = [&](int mh){
      #pragma unroll
      for(int m = 0; m < 4; ++m){
        int row = wr * 128 + (mh * 4 + m) * 16 + fr;
        af[m] = *(const s16x8*)&Al[row * 32 + swz32(row, fc)];
      }
    };
    auto loadB = [&](int nh, s16x8* bf){
      #pragma unroll
      for(int n = 0; n < 2; ++n){
        int row = wc * 64 + (nh * 2 + n) * 16 + fr;
        bf[n] = *(const s16x8*)&Bl[row * 32 + swz32(row, fc)];
      }
    };
    auto mm = [&](int mh, int nh, s16x8* bf){
      __builtin_amdgcn_s_setprio(1);
      #pragma unroll
      for(int m = 0; m < 4; ++m)
        #pragma unroll
        for(int n = 0; n < 2; ++n)
          acc[mh * 4 + m][nh * 2 + n] = __builtin_amdgcn_mfma_f32_16x16x32_bf16(
              af[m], bf[n], acc[mh * 4 + m][nh * 2 + n], 0, 0, 0);
      __builtin_amdgcn_s_setprio(0);
    };

    loadA(0); loadB(0, bf0); mm(0, 0, bf0);
    loadB(1, bf1);           mm(0, 1, bf1);
    loadA(1);                mm(1, 1, bf1);
    loadB(0, bf0);           mm(1, 0, bf0);
    asm volatile("s_barrier" ::: "memory");
  }

  float bb[4];
  #pragma unroll
  for(int n = 0; n < 4; ++n)
    bb[n] = bias[wh * 768 + colB0 + wc * 64 + n * 16 + fr];

  short* Cs = &lds[0][0];
  #pragma unroll
  for(int ch = 0; ch < 2; ++ch){
    __syncthreads();
    if(wr == ch){
      #pragma unroll
      for(int m = 0; m < 8; ++m)
        #pragma unroll
        for(int n = 0; n < 4; ++n)
          #pragma unroll
          for(int r2 = 0; r2 < 4; ++r2){
            int row = m * 16 + (lane >> 4) * 4 + r2;
            int c = wc * 64 + n * 16 + fr;
            Cs[row * 256 + (c ^ (((row >> 2) & 3) << 4))] = f2bf(acc[m][n][r2] + bb[n]);
          }
    }
    __syncthreads();
    #pragma unroll
    for(int i = 0; i < 8; ++i){
      int idx = i * 512 + tid;
      int row = idx >> 5, cl = (idx & 31) * 8;
      s16x8 v = *(const s16x8*)&Cs[row * 256 + (cl ^ (((row >> 2) & 3) << 4))];
      *(s16x8*)&Out[(rowA0 + ch * 128 + row) * 768 + colB0 + cl] = v;
    }
  }
}

// ------ fallback final (fp32 out, 128² 2-phase, proven) ------
__global__ __launch_bounds__(256, 2) void gemm_f32(const short* __restrict__ A,
                                                   const short* __restrict__ B,
                                                   const float* __restrict__ bias,
                                                   float* __restrict__ Cout){
  __shared__ short smem[4 * 8192];
  const int tid = threadIdx.x, lane = tid & 63, w = tid >> 6;
  const int wr = w >> 1, wc = w & 1;
  const int nCol = 6;
  const int xcd = blockIdx.x & 7, loc = blockIdx.x >> 3;
  const int width = nCol << 3;
  const int gid = loc / width, rem = loc % width;
  const int rowBlk = (xcd << 6) + (gid << 3) + (rem & 7);
  const int colBlk = rem >> 3;
  const long rowA0 = (long)rowBlk << 7;
  const long colB0 = (long)colBlk << 7;
  const int lr = lane >> 3;
  const int sA = swz64(lr, (lane & 7) * 8);

  f32x4 acc[4][4] = {};
  auto stage = [&](int b, int kt){
    short* As = smem + b * 16384;
    #pragma unroll
    for(int it = 0; it < 4; ++it){
      int r = it * 32 + w * 8;
      gld_lds16(&A[(rowA0 + r + lr) * 768 + kt + sA], &As[r * 64]);
      gld_lds16(&B[(colB0 + r + lr) * 768 + kt + sA], &As[8192 + r * 64]);
    }
  };

  stage(0, 0);
  for(int t = 0; t < 12; ++t){
    const int cur = t & 1;
    if(t < 11){
      stage(cur ^ 1, (t + 1) * 64);
      asm volatile("s_waitcnt vmcnt(8)\n\ts_barrier" ::: "memory");
    } else {
      asm volatile("s_waitcnt vmcnt(0)\n\ts_barrier" ::: "memory");
    }
    const short* As = smem + cur * 16384;
    const short* Bs = As + 8192;
    #pragma unroll
    for(int kk = 0; kk < 2; ++kk){
      s16x8 af[4], bfr[4];
      #pragma unroll
      for(int m = 0; m < 4; ++m){
        int row = wr * 64 + m * 16 + (lane & 15);
        af[m] = *(const s16x8*)&As[row * 64 + swz64(row, kk * 32 + (lane >> 4) * 8)];
      }
      #pragma unroll
      for(int n = 0; n < 4; ++n){
        int row = wc * 64 + n * 16 + (lane & 15);
        bfr[n] = *(const s16x8*)&Bs[row * 64 + swz64(row, kk * 32 + (lane >> 4) * 8)];
      }
      #pragma unroll
      for(int m = 0; m < 4; ++m)
        #pragma unroll
        for(int n = 0; n < 4; ++n)
          acc[m][n] = __builtin_amdgcn_mfma_f32_16x16x32_bf16(af[m], bfr[n], acc[m][n], 0, 0, 0);
    }
    asm volatile("s_barrier" ::: "memory");
  }

  const long crow0 = rowA0 + wr * 64;
  const long ccol0 = colB0 + wc * 64;
  #pragma unroll
  for(int n = 0; n < 4; ++n){
    const long col = ccol0 + n * 16 + (lane & 15);
    const float bbv = bias[col];
    #pragma unroll
    for(int m = 0; m < 4; ++m)
      #pragma unroll
      for(int r = 0; r < 4; ++r){
        const long row = crow0 + m * 16 + (lane >> 4) * 4 + r;
        Cout[row * 768 + col] = acc[m][n][r] + bbv;
      }
  }
}

// ------ fused per-(h,s): scores = Q@Xs^T (4-phase) ; V' = scores@P ; -> Cat ------
__global__ __launch_bounds__(256, 2) void attn_k(const short* __restrict__ Q,
                                                 const short* __restrict__ P,
                                                 const short* __restrict__ X,
                                                 short* __restrict__ Cat,
                                                 int h0, int nH){
  __shared__ short smem[4 * 8192];   // 2 bufs × (Q 8192 | X 8192 shorts)
  const int tid = threadIdx.x, lane = tid & 63, w = tid >> 6;
  const int wr = w >> 1, wc = w & 1;
  const int nwg = nH << 9;
  const int bid = xcd_swz(blockIdx.x, nwg);
  const int s = bid / nH, hi = bid - s * nH, h = h0 + hi;
  const long row0 = (long)s * 128;

  // P-tile prefetch to regs (consumed after QK^T)
  const int pm = tid >> 3, pt0 = (tid & 7) * 8;
  s16x8 pv[4];
  #pragma unroll
  for(int i = 0; i < 4; ++i)
    pv[i] = *(const s16x8*)&P[(row0 + pm + i * 32) * 768L + h * 64 + pt0];

  const short* Qh = Q + (long)hi * SLOT;
  const int srow = tid >> 3;                    // 0..31
  const int ssw = swz64(srow, (tid & 7) * 8);
  const short* gQ = Qh + (row0 + srow) * 768 + ssw;
  const short* gX = X + (row0 + srow) * 768 + ssw;

  // stage quarter j (rows j*32..j*32+31 of both Q and X): 2 gld_lds/thread
  auto stageQX = [&](int b, int kt, int j){
    short* As = smem + b * 16384;
    gld_lds16(gQ + (long)j * 24576 + kt, As + j * 2048 + w * 512);
    gld_lds16(gX + (long)j * 24576 + kt, As + 8192 + j * 2048 + w * 512);
  };

  f32x4 acc[4][4] = {};
  const int fr = lane & 15, fcb = (lane >> 4) * 8;
  s16x8 af[2][2], bf[2][2];

  auto readAq = [&](int b, int mh){
    const short* Al = smem + b * 16384;
    #pragma unroll
    for(int m = 0; m < 2; ++m){
      int row = wr * 64 + (mh * 2 + m) * 16 + fr;
      #pragma unroll
      for(int kk = 0; kk < 2; ++kk)
        af[m][kk] = *(const s16x8*)&Al[row * 64 + swz64(row, kk * 32 + fcb)];
    }
  };
  auto readBq = [&](int b, int nh){
    const short* Bl = smem + b * 16384 + 8192;
    #pragma unroll
    for(int n = 0; n < 2; ++n){
      int row = wc * 64 + (nh * 2 + n) * 16 + fr;
      #pragma unroll
      for(int kk = 0; kk < 2; ++kk)
        bf[n][kk] = *(const s16x8*)&Bl[row * 64 + swz64(row, kk * 32 + fcb)];
    }
  };
  auto mmq = [&](int mh, int nh){
    asm volatile("s_waitcnt lgkmcnt(0)" ::: "memory");
    __builtin_amdgcn_s_setprio(1);
    #pragma unroll
    for(int m = 0; m < 2; ++m)
      #pragma unroll
      for(int n = 0; n < 2; ++n)
        #pragma unroll
        for(int kk = 0; kk < 2; ++kk)
          acc[mh*2+m][nh*2+n] = __builtin_amdgcn_mfma_f32_16x16x32_bf16(
              af[m][kk], bf[n][kk], acc[mh*2+m][nh*2+n], 0, 0, 0);
    __builtin_amdgcn_s_setprio(0);
  };

  stageQX(0, 0, 0); stageQX(0, 0, 1); stageQX(0, 0, 2); stageQX(0, 0, 3);

  for(int t = 0; t < 12; ++t){
    const int b = t & 1, nb = b ^ 1;
    const int kt1 = (t + 1) * 64;
    if(t < 11){
      stageQX(nb, kt1, 0);
      asm volatile("s_waitcnt vmcnt(2)" ::: "memory");
    } else {
      asm volatile("s_waitcnt vmcnt(0)" ::: "memory");
    }
    asm volatile("s_barrier" ::: "memory");
    readAq(b, 0); readBq(b, 0);
    mmq(0, 0);
    asm volatile("s_barrier" ::: "memory");
    readBq(b, 1);
    if(t < 11) stageQX(nb, kt1, 1);
    asm volatile("s_barrier" ::: "memory");
    mmq(0, 1);
    asm volatile("s_barrier" ::: "memory");
    readAq(b, 1);
    if(t < 11) stageQX(nb, kt1, 2);
    asm volatile("s_barrier" ::: "memory");
    mmq(1, 1);
    asm volatile("s_barrier" ::: "memory");
    readBq(b, 0);
    if(t < 11) stageQX(nb, kt1, 3);
    asm volatile("s_barrier" ::: "memory");
    mmq(1, 0);
    asm volatile("s_barrier" ::: "memory");
  }

  asm volatile("s_waitcnt vmcnt(0) lgkmcnt(0)" ::: "memory");
  __syncthreads();

  short* Pt = smem;           // [64][128]
  short* Vt = smem + 8192;    // [128][64]
  short* Ss = smem + 16384;   // [128][128]

  #pragma unroll
  for(int m = 0; m < 4; ++m)
    #pragma unroll
    for(int n = 0; n < 4; ++n)
      #pragma unroll
      for(int r = 0; r < 4; ++r){
        int row = wr * 64 + m * 16 + (lane >> 4) * 4 + r;
        int c = wc * 64 + n * 16 + (lane & 15);
        Ss[row * 128 + swz64(row, c)] = f2bf(acc[m][n][r]);
      }
  #pragma unroll
  for(int i = 0; i < 4; ++i)
    #pragma unroll
    for(int j = 0; j < 8; ++j){
      int trow = pt0 + j;
      int mc = pm + i * 32;
      Pt[trow * 128 + swz64(trow, mc)] = pv[i][j];
    }
  __syncthreads();

  f32x4 accv[2][4] = {};
  #pragma unroll
  for(int kk = 0; kk < 4; ++kk){
    s16x8 a2[2], b4[4];
    #pragma unroll
    for(int m = 0; m < 2; ++m){
      int row = w * 32 + m * 16 + (lane & 15);
      a2[m] = *(const s16x8*)&Ss[row * 128 + swz64(row, kk * 32 + (lane >> 4) * 8)];
    }
    #pragma unroll
    for(int n = 0; n < 4; ++n){
      int trow = n * 16 + (lane & 15);
      b4[n] = *(const s16x8*)&Pt[trow * 128 + swz64(trow, kk * 32 + (lane >> 4) * 8)];
    }
    #pragma unroll
    for(int m = 0; m < 2; ++m)
      #pragma unroll
      for(int n = 0; n < 4; ++n)
        accv[m][n] = __builtin_amdgcn_mfma_f32_16x16x32_bf16(a2[m], b4[n], accv[m][n], 0, 0, 0);
  }

  #pragma unroll
  for(int m = 0; m < 2; ++m)
    #pragma unroll
    for(int n = 0; n < 4; ++n)
      #pragma unroll
      for(int r = 0; r < 4; ++r){
        int row = w * 32 + m * 16 + (lane >> 4) * 4 + r;
        int c = n * 16 + (lane & 15);
        Vt[row * 64 + swz64(row, c)] = f2bf(accv[m][n][r]);
      }
  __syncthreads();
  #pragma unroll
  for(int k2 = 0; k2 < 4; ++k2){
    int row = k2 * 32 + (tid >> 3);
    int cl = (tid & 7) * 8;
    s16x8 v = *(const s16x8*)&Vt[row * 64 + swz64(row, cl)];
    *(s16x8*)&Cat[(row0 + row) * 768L + h * 64 + cl] = v;
  }
}

extern "C" void kernel_launch(void* const* d_in, const int* in_sizes, int n_in,
                              void* d_out, int out_size, void* d_ws, size_t ws_size,
                              hipStream_t stream){
  const float* x  = (const float*)d_in[0];
  const float* Wq = (const float*)d_in[1];
  const float* bq = (const float*)d_in[2];
  const float* Wv = (const float*)d_in[3];
  const float* bv = (const float*)d_in[4];
  const float* Wf = (const float*)d_in[5];
  const float* bfv= (const float*)d_in[6];

  const float rsqE = 0.03608439182435161f;  // 1/sqrt(768)
  char* ws = (char*)d_ws;

  short* Xb  = (short*)(ws);
  short* Cat = (short*)(ws + 100663296L);
  short* Wb  = (short*)(ws + 201326592L);   // [13*768][768] bf16
  short* Wfb = (short*)(ws + 216662016L);
  float* bQP = (float*)(ws + 217841664L);   // [9984]
  float* cv  = (float*)(ws + 217881600L);
  short* QS  = (short*)(ws + 217884672L);   // (G+1) slots of [65536][768]

  const size_t QOFF = 217884672ULL;
  int G = 1;
  const int cands[5] = {12, 6, 4, 3, 2};
  for(int i = 0; i < 5; ++i)
    if(ws_size >= QOFF + (size_t)(cands[i] + 1) * 100663296ULL){ G = cands[i]; break; }
  short* Pall = QS + (long)G * SLOT;

  // opt-in to 128 KiB dynamic LDS; fall back if unavailable
  bool deep =
      hipFuncSetAttribute(reinterpret_cast<const void*>(&gemm8p<false>),
                          hipFuncAttributeMaxDynamicSharedMemorySize, 131072) == hipSuccess &&
      hipFuncSetAttribute(reinterpret_cast<const void*>(&gemm8p<true>),
                          hipFuncAttributeMaxDynamicSharedMemorySize, 131072) == hipSuccess;

  dim3 b256(256), b512(512);
  cast_bf16_k<<<24576, b256, 0, stream>>>(x,  Xb, 50331648L, 1.f);
  cast_bf16_k<<<3456,  b256, 0, stream>>>(Wq, Wb, 7077888L, 1.f);
  cast_bf16_k<<<288,   b256, 0, stream>>>(Wv, Wb + 7077888L, 589824L, rsqE);
  cast_bf16_k<<<288,   b256, 0, stream>>>(Wf, Wfb, 589824L, 1.f);
  bias_build<<<39, b256, 0, stream>>>(bq, bQP);
  cvec_k<<<3, b256, 0, stream>>>(Wf, bv, bfv, cv);

  const int nB = 12 / G;
  for(int b = 0; b < nB; ++b){
    const int nSub = G + (b == 0 ? 1 : 0);
    const int pSub = (b == 0) ? G : -1;
    if(deep)
      gemm8p<false><<<dim3(nSub * 768), b512, 131072, stream>>>(Xb, Wb, bQP, QS, b * G, nSub, pSub);
    else
      gemm256<<<dim3(nSub * 768), b512, 0, stream>>>(Xb, Wb, bQP, QS, b * G, nSub, pSub);
    attn_k<<<dim3(G * 512), b256, 0, stream>>>(QS, Pall, Xb, Cat, b * G, G);
  }
  if(deep)
    gemm8p<true><<<dim3(768), b512, 131072, stream>>>(Cat, Wfb, cv, d_out, 0, 1, -1);
  else
    gemm_f32<<<dim3(3072), b256, 0, stream>>>(Cat, Wfb, cv, (float*)d_out);
}